// Round 6
// baseline (8463.062 us; speedup 1.0000x reference)
//
#include <hip/hip_runtime.h>

// ---------------- types ----------------
using f16   = _Float16;
using f16x8 = __attribute__((ext_vector_type(8))) _Float16;
using f32x4 = __attribute__((ext_vector_type(4))) float;

#define MPAD  18560          // 145*128, padded token rows
#define MREAL 18464          // 32*577
#define MCONV 18432          // 32*576
#define SEQ   577
#define SPAD  640
#define NHEAD 12
#define NBATCH 32
#define SCALE_ 0.125f        // 1/sqrt(64)

__device__ __forceinline__ void load_lds16(const void* g, void* l) {
  __builtin_amdgcn_global_load_lds(
      (const __attribute__((address_space(1))) void*)g,
      (__attribute__((address_space(3))) void*)l, 16, 0, 0);
}

// ---------------- GEMM: C[M,N] = A[M,K] * Bt[N,K]^T, fused epilogues ----------------
// Round-1/5 compute structure (BK=32, 128^2 tile, 4 waves) with a 3-deep LDS
// pipeline: stage tile t+2 before computing tile t; end-of-step wait is
// s_waitcnt vmcnt(4) (tile t+2's 4 loads stay in flight across the barrier,
// only tile t+1's loads -- issued 2 steps ago -- are waited on). Ledger:
//   per step issue exactly 4 global_load_lds (2 A + 2 B).
//   buffer written at step t was last read at step t-3, freed by the t-3
//   barrier -> no write-while-read race.
// Block ordering: bijective XCD chunking (m204) + M-major decode within
// 6-N-tile bands (B band L2-resident). Requires gridDim.x % 6 == 0.
// EPI 0: conv embed (scramble + conv_b + pos_emb -> o32=X)
// EPI 1: qkv scatter (bias; q->o16a [bh][s][e], k->o16b [bh][s][e], v->o16c [bh][e][s])
// EPI 2: bias + residual -> o32 (fp32)
// EPI 3: bias + exact gelu -> o16a (fp16)
template<int K, int EPI>
__global__ __launch_bounds__(256) void gemm_k(
    const f16* __restrict__ A, const f16* __restrict__ Bt,
    const float* __restrict__ bias, const float* __restrict__ res,
    float* __restrict__ o32, f16* __restrict__ o16a, f16* __restrict__ o16b,
    f16* __restrict__ o16c, const float* __restrict__ pos, int N, int Mreal)
{
  static_assert(K % 32 == 0, "BK=32");
  constexpr int NT = K / 32;
  __shared__ __align__(16) f16 As[3][128 * 32];
  __shared__ __align__(16) f16 Bs[3][128 * 32];
  const int tid = threadIdx.x;
  const int lane = tid & 63, wv = tid >> 6;

  // XCD chunking + band-supertile decode
  const int gx = gridDim.x, gy = gridDim.y;
  const int nwg = gx * gy;
  const int flat = blockIdx.y * gx + blockIdx.x;
  const int xcd = flat & 7;
  const int qq = nwg >> 3, rr = nwg & 7;
  const int p_ = ((xcd < rr) ? xcd * (qq + 1) : rr * (qq + 1) + (xcd - rr) * qq)
                 + (flat >> 3);
  const int bandsz = gy * 6;
  const int band = p_ / bandsz, within = p_ - band * bandsz;
  const int byi = within / 6;
  const int bxi = band * 6 + (within - byi * 6);
  const int bm = byi << 7, bn = bxi << 7;

  const int wm = (wv >> 1) << 6, wn = (wv & 1) << 6;
  const int r16 = lane & 15, g4 = lane >> 4;
  const f32x4 Z4 = {0.f, 0.f, 0.f, 0.f};

  f32x4 acc[4][4];
#pragma unroll
  for (int m = 0; m < 4; ++m)
#pragma unroll
    for (int n = 0; n < 4; ++n) acc[m][n] = Z4;

  // staging addressing (precomputed per-lane base pointers; k0 is the only
  // loop-variant term). Layout identical to round-5 (verified correct).
  const int soff = wv * 1024 + lane * 8;          // halves
  const int r0   = soff >> 5;                     // 0..127
  const int gc0  = ((soff >> 3) & 3) ^ (r0 & 3);  // pre-swizzled global chunk
  const f16* Agp = A  + (size_t)(bm + r0) * K + gc0 * 8;
  const f16* Bgp = Bt + (size_t)(bn + r0) * K + gc0 * 8;
  const int ldso = wv * 1024;

  auto stage = [&](f16* Ad, f16* Bd, int k0) {
    load_lds16(Agp + k0,                  Ad + ldso);
    load_lds16(Agp + (size_t)16 * K + k0, Ad + ldso + 512);
    load_lds16(Bgp + k0,                  Bd + ldso);
    load_lds16(Bgp + (size_t)16 * K + k0, Bd + ldso + 512);
  };

  f16 *A0 = As[0], *A1 = As[1], *A2 = As[2];
  f16 *B0 = Bs[0], *B1 = Bs[1], *B2 = Bs[2];
  stage(A0, B0, 0);
  stage(A1, B1, 32);
  asm volatile("s_waitcnt vmcnt(4)" ::: "memory");  // tile0 done; tile1 in flight
  __builtin_amdgcn_s_barrier();

#pragma unroll 1
  for (int t = 0; t < NT; ++t) {
    const bool pf = (t + 2 < NT);
    if (pf) stage(A2, B2, (t + 2) * 32);   // into buffer freed at step t-1
    f16x8 af[4], bf[4];
#pragma unroll
    for (int m = 0; m < 4; ++m) {
      int row = wm + m * 16 + r16;
      af[m] = *(const f16x8*)(A0 + row * 32 + ((g4 ^ (row & 3)) << 3));
    }
#pragma unroll
    for (int n = 0; n < 4; ++n) {
      int row = wn + n * 16 + r16;
      bf[n] = *(const f16x8*)(B0 + row * 32 + ((g4 ^ (row & 3)) << 3));
    }
#pragma unroll
    for (int m = 0; m < 4; ++m)
#pragma unroll
      for (int n = 0; n < 4; ++n)
        acc[m][n] = __builtin_amdgcn_mfma_f32_16x16x32_f16(af[m], bf[n], acc[m][n], 0, 0, 0);
    if (pf) { asm volatile("s_waitcnt vmcnt(4)" ::: "memory"); }  // t+1 ready, t+2 in flight
    else    { asm volatile("s_waitcnt vmcnt(0)" ::: "memory"); }  // tail: drain
    __builtin_amdgcn_s_barrier();
    f16* ta = A0; A0 = A1; A1 = A2; A2 = ta;
    f16* tb = B0; B0 = B1; B1 = B2; B2 = tb;
  }

#pragma unroll
  for (int m = 0; m < 4; ++m) {
#pragma unroll
    for (int n = 0; n < 4; ++n) {
#pragma unroll
      for (int r = 0; r < 4; ++r) {
        int grow = bm + wm + m * 16 + g4 * 4 + r;
        int gcol = bn + wn + n * 16 + r16;
        float v = acc[m][n][r];
        if constexpr (EPI == 0) {
          if (grow < Mreal) {
            int b = grow / 576, p = grow - b * 576;
            int i = gcol * 576 + p;               // channel-major flat index
            int sp = i / 768, dd = i - sp * 768;  // faithful .view(b,-1,D) scramble
            o32[((size_t)(b * SEQ + sp + 1)) * 768 + dd] =
                v + bias[gcol] + pos[(size_t)(sp + 1) * 768 + dd];
          }
        } else if constexpr (EPI == 1) {
          if (grow < Mreal) {
            int b = grow / SEQ, s = grow - b * SEQ;
            int hq = gcol / 192, rem = gcol - hq * 192;
            int sel = rem >> 6, e = rem & 63;
            float val = v + bias[gcol];
            int bh = b * NHEAD + hq;
            if (sel == 0)      o16a[((size_t)bh * SPAD + s) * 64 + e] = (f16)val;
            else if (sel == 1) o16b[((size_t)bh * SPAD + s) * 64 + e] = (f16)val;
            else               o16c[((size_t)bh * 64 + e) * SPAD + s] = (f16)val;  // V transposed
          }
        } else if constexpr (EPI == 2) {
          size_t idx = (size_t)grow * N + gcol;
          o32[idx] = v + bias[gcol] + res[idx];
        } else {
          float val = v + bias[gcol];
          float gl = 0.5f * val * (1.0f + erff(val * 0.70710678f));
          o16a[(size_t)grow * N + gcol] = (f16)gl;
        }
      }
    }
  }
}

// ---------------- block reduce helper ----------------
__device__ __forceinline__ void block_red2(float& a, float& b, float* sm, int tid) {
  __syncthreads();
#pragma unroll
  for (int d = 32; d; d >>= 1) { a += __shfl_down(a, d); b += __shfl_down(b, d); }
  if ((tid & 63) == 0) { int w = tid >> 6; sm[w] = a; sm[w + 4] = b; }
  __syncthreads();
  a = sm[0] + sm[1] + sm[2] + sm[3];
  b = sm[4] + sm[5] + sm[6] + sm[7];
}

// ---------------- LayerNorm (fp32 in -> fp32 + fp16 out) ----------------
__global__ __launch_bounds__(256) void ln_fwd(const float* __restrict__ X,
    const float* __restrict__ g, const float* __restrict__ bb,
    float* __restrict__ ho, f16* __restrict__ hh)
{
  int row = blockIdx.x, tid = threadIdx.x;
  const float* x = X + (size_t)row * 768;
  float v0 = x[tid], v1 = x[tid + 256], v2 = x[tid + 512];
  float s = v0 + v1 + v2, s2 = v0*v0 + v1*v1 + v2*v2;
  __shared__ float sm[8];
  block_red2(s, s2, sm, tid);
  float mu = s * (1.f/768.f);
  float var = s2 * (1.f/768.f) - mu * mu;
  float rs = rsqrtf(var + 1e-5f);
  size_t base = (size_t)row * 768;
  float y0 = (v0 - mu) * rs * g[tid      ] + bb[tid      ];
  float y1 = (v1 - mu) * rs * g[tid + 256] + bb[tid + 256];
  float y2 = (v2 - mu) * rs * g[tid + 512] + bb[tid + 512];
  ho[base + tid] = y0; ho[base + tid + 256] = y1; ho[base + tid + 512] = y2;
  hh[base + tid] = (f16)y0; hh[base + tid + 256] = (f16)y1; hh[base + tid + 512] = (f16)y2;
}

// ---------------- Double LayerNorm (LN(LN(x))) -> fp16 ----------------
__global__ __launch_bounds__(256) void ln2_fwd(const float* __restrict__ X,
    const float* __restrict__ g2, const float* __restrict__ bb2,
    const float* __restrict__ gm, const float* __restrict__ bbm,
    f16* __restrict__ hh)
{
  int row = blockIdx.x, tid = threadIdx.x;
  const float* x = X + (size_t)row * 768;
  float v0 = x[tid], v1 = x[tid + 256], v2 = x[tid + 512];
  float s = v0 + v1 + v2, s2 = v0*v0 + v1*v1 + v2*v2;
  __shared__ float sm[8];
  block_red2(s, s2, sm, tid);
  float mu = s * (1.f/768.f), var = s2 * (1.f/768.f) - mu * mu;
  float rs = rsqrtf(var + 1e-5f);
  float y0 = (v0 - mu) * rs * g2[tid      ] + bb2[tid      ];
  float y1 = (v1 - mu) * rs * g2[tid + 256] + bb2[tid + 256];
  float y2 = (v2 - mu) * rs * g2[tid + 512] + bb2[tid + 512];
  s = y0 + y1 + y2; s2 = y0*y0 + y1*y1 + y2*y2;
  block_red2(s, s2, sm, tid);
  mu = s * (1.f/768.f); var = s2 * (1.f/768.f) - mu * mu;
  rs = rsqrtf(var + 1e-5f);
  size_t base = (size_t)row * 768;
  hh[base + tid      ] = (f16)((y0 - mu) * rs * gm[tid      ] + bbm[tid      ]);
  hh[base + tid + 256] = (f16)((y1 - mu) * rs * gm[tid + 256] + bbm[tid + 256]);
  hh[base + tid + 512] = (f16)((y2 - mu) * rs * gm[tid + 512] + bbm[tid + 512]);
}

// ---------------- flash attention (64 q-rows / block, online softmax) ----------------
__global__ __launch_bounds__(256) void attn_k(const f16* __restrict__ qbuf,
    const f16* __restrict__ kbuf, const f16* __restrict__ vtbuf,
    f16* __restrict__ obuf)
{
  const int bh = blockIdx.y;
  const int b = bh / NHEAD, hd = bh - b * NHEAD;
  const int s0 = blockIdx.x << 6;
  const int tid = threadIdx.x, lane = tid & 63, wv = tid >> 6;
  const int r16 = lane & 15, g4 = lane >> 4;
  const f16* Q  = qbuf  + (size_t)bh * SPAD * 64;
  const f16* Kg = kbuf  + (size_t)bh * SPAD * 64;
  const f16* Vg = vtbuf + (size_t)bh * 64 * SPAD;
  __shared__ __align__(16) f16 Kt[64 * 64];
  __shared__ __align__(16) f16 Vt[64 * 64];
  __shared__ __align__(16) f16 Pw[4][16][72];
  const f32x4 Z4 = {0.f, 0.f, 0.f, 0.f};

  f16x8 qf[2];
  {
    const f16* qr = Q + (size_t)(s0 + wv * 16 + r16) * 64;
    qf[0] = *(const f16x8*)(qr + g4 * 8);
    qf[1] = *(const f16x8*)(qr + 32 + g4 * 8);
  }
  float m_run[4] = {-1e30f, -1e30f, -1e30f, -1e30f};
  float l_run[4] = {0.f, 0.f, 0.f, 0.f};
  f32x4 o_acc[4];
#pragma unroll
  for (int n = 0; n < 4; ++n) o_acc[n] = Z4;

  for (int kt = 0; kt < SPAD; kt += 64) {
#pragma unroll
    for (int j = 0; j < 2; ++j) {
      int off = (wv * 2 + j) * 1024 + lane * 16;  // bytes
      int row = off >> 7;
      int cs  = (off >> 4) & 7;
      int gc  = cs ^ (row & 7);                   // 8-chunk XOR swizzle
      load_lds16(Kg + (size_t)(kt + row) * 64 + gc * 8, (void*)((char*)Kt + (wv*2 + j) * 1024));
      load_lds16(Vg + (size_t)row * SPAD + kt + gc * 8, (void*)((char*)Vt + (wv*2 + j) * 1024));
    }
    __syncthreads();

    f32x4 sa[4];
#pragma unroll
    for (int n = 0; n < 4; ++n) sa[n] = Z4;
#pragma unroll
    for (int n = 0; n < 4; ++n) {
      int krow = n * 16 + r16;
#pragma unroll
      for (int kc = 0; kc < 2; ++kc) {
        f16x8 kf = *(const f16x8*)(Kt + krow * 64 + (((kc * 4 + g4) ^ (krow & 7)) << 3));
        sa[n] = __builtin_amdgcn_mfma_f32_16x16x32_f16(qf[kc], kf, sa[n], 0, 0, 0);
      }
    }
#pragma unroll
    for (int r = 0; r < 4; ++r) {
      float mx = -1e30f;
#pragma unroll
      for (int n = 0; n < 4; ++n) {
        int key = kt + n * 16 + r16;
        float sv = (key < SEQ) ? sa[n][r] * SCALE_ : -1e30f;
        sa[n][r] = sv;
        mx = fmaxf(mx, sv);
      }
#pragma unroll
      for (int d = 1; d < 16; d <<= 1) mx = fmaxf(mx, __shfl_xor(mx, d));
      float mnew = fmaxf(m_run[r], mx);
      float alpha = __expf(m_run[r] - mnew);
      m_run[r] = mnew;
      float ssum = 0.f;
#pragma unroll
      for (int n = 0; n < 4; ++n) {
        float p = __expf(sa[n][r] - mnew);
        ssum += p;
        Pw[wv][g4 * 4 + r][n * 16 + r16] = (f16)p;
      }
#pragma unroll
      for (int d = 1; d < 16; d <<= 1) ssum += __shfl_xor(ssum, d);
      l_run[r] = l_run[r] * alpha + ssum;
#pragma unroll
      for (int n = 0; n < 4; ++n) o_acc[n][r] *= alpha;
    }
    f16x8 pf[2];
    pf[0] = *(const f16x8*)(&Pw[wv][r16][g4 * 8]);
    pf[1] = *(const f16x8*)(&Pw[wv][r16][32 + g4 * 8]);
#pragma unroll
    for (int n = 0; n < 4; ++n) {
      int erow = n * 16 + r16;
#pragma unroll
      for (int kc = 0; kc < 2; ++kc) {
        f16x8 vf = *(const f16x8*)(Vt + erow * 64 + (((kc * 4 + g4) ^ (erow & 7)) << 3));
        o_acc[n] = __builtin_amdgcn_mfma_f32_16x16x32_f16(pf[kc], vf, o_acc[n], 0, 0, 0);
      }
    }
    __syncthreads();
  }
  float inv[4];
#pragma unroll
  for (int r = 0; r < 4; ++r) inv[r] = 1.f / l_run[r];
#pragma unroll
  for (int n = 0; n < 4; ++n)
#pragma unroll
    for (int r = 0; r < 4; ++r) {
      int s = s0 + wv * 16 + g4 * 4 + r;
      if (s < SEQ)
        obuf[((size_t)(b * SEQ + s)) * 768 + hd * 64 + n * 16 + r16] =
            (f16)(o_acc[n][r] * inv[r]);
    }
}

// ---------------- weight converts (blockIdx.z = layer) ----------------
__global__ __launch_bounds__(256) void cvt_transpose(const float* __restrict__ in,
    f16* __restrict__ out, int K, int N, size_t ls_in, size_t ls_out)
{
  in  += (size_t)blockIdx.z * ls_in;
  out += (size_t)blockIdx.z * ls_out;
  __shared__ float t[32][33];
  int n0 = blockIdx.x << 5, k0 = blockIdx.y << 5;
  int tx = threadIdx.x & 31, ty = threadIdx.x >> 5;
#pragma unroll
  for (int i = 0; i < 4; ++i) t[ty + 8*i][tx] = in[(size_t)(k0 + ty + 8*i) * N + n0 + tx];
  __syncthreads();
#pragma unroll
  for (int i = 0; i < 4; ++i) out[(size_t)(n0 + ty + 8*i) * K + k0 + tx] = (f16)t[tx][ty + 8*i];
}

__global__ __launch_bounds__(256) void cvt_qkvw(const float* __restrict__ in,
    f16* __restrict__ out, size_t ls_in, size_t ls_out)
{
  in  += (size_t)blockIdx.z * ls_in;
  out += (size_t)blockIdx.z * ls_out;
  __shared__ float t[32][33];
  int n0 = blockIdx.x << 5, k0 = blockIdx.y << 5;
  int tx = threadIdx.x & 31, ty = threadIdx.x >> 5;
  int hq = n0 / 192, r0 = n0 - hq * 192;
#pragma unroll
  for (int i = 0; i < 4; ++i)
    t[ty + 8*i][tx] = in[(size_t)hq * 147456 + (size_t)(k0 + ty + 8*i) * 192 + r0 + tx];
  __syncthreads();
#pragma unroll
  for (int i = 0; i < 4; ++i) out[(size_t)(n0 + ty + 8*i) * 768 + k0 + tx] = (f16)t[tx][ty + 8*i];
}

__global__ __launch_bounds__(256) void cvt_plain(const float* __restrict__ in,
    f16* __restrict__ out, int n)
{
  int i = blockIdx.x * 1024 + threadIdx.x;
#pragma unroll
  for (int j = 0; j < 4; ++j) { int idx = i + j * 256; if (idx < n) out[idx] = (f16)in[idx]; }
}

__global__ __launch_bounds__(256) void zero_vpad(f16* __restrict__ vtb) {
  int bh = blockIdx.x;
  for (int idx = threadIdx.x; idx < 64 * (SPAD - SEQ); idx += 256) {
    int e = idx / (SPAD - SEQ), s = SEQ + idx - e * (SPAD - SEQ);
    vtb[((size_t)bh * 64 + e) * SPAD + s] = (f16)0.f;
  }
}

// ---------------- patchify (im2col) & cls ----------------
__global__ __launch_bounds__(256) void im2col_k(const float* __restrict__ x, f16* __restrict__ out) {
  int row = blockIdx.x;
  int b = row / 576, p = row - b * 576;
  int py = p / 24, px = p - py * 24;
  int tid = threadIdx.x;
#pragma unroll
  for (int j = 0; j < 3; ++j) {
    int k = tid + j * 256;
    int c = k >> 8, rem = k & 255;
    int iy = rem >> 4, ix = rem & 15;
    out[(size_t)row * 768 + k] =
        (f16)x[(((size_t)(b * 3 + c)) * 384 + py * 16 + iy) * 384 + px * 16 + ix];
  }
}

__global__ __launch_bounds__(256) void cls_k(const float* __restrict__ ct,
    const float* __restrict__ pos, float* __restrict__ X)
{
  int b = blockIdx.x, tid = threadIdx.x;
#pragma unroll
  for (int j = 0; j < 3; ++j) {
    int d0 = tid + j * 256;
    X[((size_t)b * SEQ) * 768 + d0] = ct[d0] + pos[d0];
  }
}

// ---------------- classifier head: logits (grid 32 x 4) + softmax (grid 32) ----------------
__global__ __launch_bounds__(256) void head_logits(const float* __restrict__ X,
    const float* __restrict__ g, const float* __restrict__ bb,
    const float* __restrict__ W, const float* __restrict__ bhd,
    float* __restrict__ lg)
{
  int b = blockIdx.x, tid = threadIdx.x;
  const float* x = X + (size_t)(b * SEQ) * 768;
  float v0 = x[tid], v1 = x[tid + 256], v2 = x[tid + 512];
  float s = v0 + v1 + v2, s2 = v0*v0 + v1*v1 + v2*v2;
  __shared__ float sm[8];
  block_red2(s, s2, sm, tid);
  float mu = s * (1.f/768.f), var = s2 * (1.f/768.f) - mu * mu;
  float rs = rsqrtf(var + 1e-5f);
  __shared__ float y[768];
  y[tid      ] = (v0 - mu) * rs * g[tid      ] + bb[tid      ];
  y[tid + 256] = (v1 - mu) * rs * g[tid + 256] + bb[tid + 256];
  y[tid + 512] = (v2 - mu) * rs * g[tid + 512] + bb[tid + 512];
  __syncthreads();
  int c = blockIdx.y * 250 + tid;
  if (tid < 250) {
    float a0 = 0.f, a1 = 0.f, a2 = 0.f, a3 = 0.f;
#pragma unroll 4
    for (int d = 0; d < 768; d += 4) {
      a0 = fmaf(y[d    ], W[(size_t)(d    ) * 1000 + c], a0);
      a1 = fmaf(y[d + 1], W[(size_t)(d + 1) * 1000 + c], a1);
      a2 = fmaf(y[d + 2], W[(size_t)(d + 2) * 1000 + c], a2);
      a3 = fmaf(y[d + 3], W[(size_t)(d + 3) * 1000 + c], a3);
    }
    lg[(size_t)b * 1000 + c] = (a0 + a1) + (a2 + a3) + bhd[c];
  }
}

__global__ __launch_bounds__(256) void head_soft(const float* __restrict__ lg,
    float* __restrict__ out)
{
  int b = blockIdx.x, tid = threadIdx.x;
  __shared__ float sm[8];
  float v[4], mx = -1e30f;
#pragma unroll
  for (int j = 0; j < 4; ++j) {
    int c = tid + j * 256;
    v[j] = (c < 1000) ? lg[(size_t)b * 1000 + c] : -1e30f;
    mx = fmaxf(mx, v[j]);
  }
#pragma unroll
  for (int d = 32; d; d >>= 1) mx = fmaxf(mx, __shfl_down(mx, d));
  if ((tid & 63) == 0) sm[tid >> 6] = mx;
  __syncthreads();
  mx = fmaxf(fmaxf(sm[0], sm[1]), fmaxf(sm[2], sm[3]));
  float se = 0.f, ex[4];
#pragma unroll
  for (int j = 0; j < 4; ++j) {
    int c = tid + j * 256;
    ex[j] = (c < 1000) ? __expf(v[j] - mx) : 0.f;
    se += ex[j];
  }
  __syncthreads();
#pragma unroll
  for (int d = 32; d; d >>= 1) se += __shfl_down(se, d);
  if ((tid & 63) == 0) sm[tid >> 6] = se;
  __syncthreads();
  se = sm[0] + sm[1] + sm[2] + sm[3];
  float inv = 1.f / se;
#pragma unroll
  for (int j = 0; j < 4; ++j) {
    int c = tid + j * 256;
    if (c < 1000) out[(size_t)b * 1000 + c] = ex[j] * inv;
  }
}

// ---------------- launcher ----------------
extern "C" void kernel_launch(void* const* d_in, const int* in_sizes, int n_in,
                              void* d_out, int out_size, void* d_ws, size_t ws_size,
                              hipStream_t stream)
{
  (void)in_sizes; (void)n_in; (void)out_size;
  const float* x      = (const float*)d_in[0];
  const float* conv_w = (const float*)d_in[1];
  const float* conv_b = (const float*)d_in[2];
  const float* cls_t  = (const float*)d_in[3];
  const float* pos    = (const float*)d_in[4];
  const float* ln1_g  = (const float*)d_in[5];
  const float* ln1_b  = (const float*)d_in[6];
  const float* wqkv   = (const float*)d_in[7];
  const float* bqkv   = (const float*)d_in[8];
  const float* wmsa   = (const float*)d_in[9];
  const float* bmsa   = (const float*)d_in[10];
  const float* ln2_g  = (const float*)d_in[11];
  const float* ln2_b  = (const float*)d_in[12];
  const float* lnm_g  = (const float*)d_in[13];
  const float* lnm_b  = (const float*)d_in[14];
  const float* w1     = (const float*)d_in[15];
  const float* b1     = (const float*)d_in[16];
  const float* w2     = (const float*)d_in[17];
  const float* b2     = (const float*)d_in[18];
  const float* lnf_g  = (const float*)d_in[19];
  const float* lnf_b  = (const float*)d_in[20];
  const float* whead  = (const float*)d_in[21];
  const float* bhead  = (const float*)d_in[22];
  float* out = (float*)d_out;

  const size_t szQ  = (size_t)2304 * 768;
  const size_t szM  = (size_t)768 * 768;
  const size_t szW1 = (size_t)3072 * 768;
  const size_t szW2 = (size_t)768 * 3072;
  const size_t fixed_bytes =
      (size_t)MPAD * 768 * 4 + (size_t)MPAD * 768 * 4 + (size_t)MPAD * 768 * 2 +
      (size_t)MPAD * 3072 * 2 + 3 * ((size_t)NBATCH * NHEAD * SPAD * 64 * 2) +
      (size_t)768 * 768 * 2 /*WcT*/ + 16 * 256 /*align slack*/;
  const bool hoist =
      ws_size >= fixed_bytes + 12 * (szQ + szM + szW1 + szW2) * 2 + 8 * 256;
  const int LW = hoist ? 12 : 1;

  char* wsp = (char*)d_ws;
  size_t off = 0;
  auto alloc = [&](size_t bytes) {
    char* p = wsp + off; off += (bytes + 255) & ~(size_t)255; return p;
  };
  float* X    = (float*)alloc((size_t)MPAD * 768 * 4);
  float* hbf  = (float*)alloc((size_t)MPAD * 768 * 4);
  f16*   hh   = (f16*)  alloc((size_t)MPAD * 768 * 2);
  f16*   abuf = (f16*)  alloc((size_t)MPAD * 3072 * 2);
  f16*   qb   = (f16*)  alloc((size_t)NBATCH * NHEAD * SPAD * 64 * 2);
  f16*   kb   = (f16*)  alloc((size_t)NBATCH * NHEAD * SPAD * 64 * 2);
  f16*   vtb  = (f16*)  alloc((size_t)NBATCH * NHEAD * SPAD * 64 * 2);
  f16*   WcT  = (f16*)  alloc((size_t)768 * 768 * 2);
  f16*   WqkvT= (f16*)  alloc(LW * szQ  * 2);
  f16*   WmsaT= (f16*)  alloc(LW * szM  * 2);
  f16*   W1T  = (f16*)  alloc(LW * szW1 * 2);
  f16*   W2T  = (f16*)  alloc(LW * szW2 * 2);
  f16*   obuf   = abuf;   // alias: attn out, consumed by MSA before FC1 writes abuf
  f16*   patchA = abuf;   // alias: im2col buffer, consumed by conv GEMM pre-loop
  f16*   h2h    = hh;     // alias: hh dead after QKV GEMM each layer
  float* lgbuf  = hbf;    // alias: head logits (hbf dead after last layer)
  if (ws_size < off) return;  // workspace too small: bail (bench will flag)

  zero_vpad<<<dim3(NBATCH * NHEAD), 256, 0, stream>>>(vtb);
  cvt_plain<<<dim3((768 * 768 + 1023) / 1024), 256, 0, stream>>>(conv_w, WcT, 768 * 768);
  if (hoist) {  // convert all 12 layers' weights up front
    cvt_qkvw<<<dim3(72, 24, 12), 256, 0, stream>>>(wqkv, WqkvT, (size_t)12*768*192, szQ);
    cvt_transpose<<<dim3(24, 24, 12), 256, 0, stream>>>(wmsa, WmsaT, 768, 768, szM, szM);
    cvt_transpose<<<dim3(96, 24, 12), 256, 0, stream>>>(w1, W1T, 768, 3072, szW1, szW1);
    cvt_transpose<<<dim3(24, 96, 12), 256, 0, stream>>>(w2, W2T, 3072, 768, szW2, szW2);
  }
  im2col_k<<<dim3(MCONV), 256, 0, stream>>>(x, patchA);
  gemm_k<768, 0><<<dim3(6, 144), 256, 0, stream>>>(
      patchA, WcT, conv_b, nullptr, X, nullptr, nullptr, nullptr, pos, 768, MCONV);
  cls_k<<<dim3(NBATCH), 256, 0, stream>>>(cls_t, pos, X);

  for (int l = 0; l < 12; ++l) {
    f16* wq  = WqkvT + (hoist ? (size_t)l * szQ  : 0);
    f16* wms = WmsaT + (hoist ? (size_t)l * szM  : 0);
    f16* w1t = W1T   + (hoist ? (size_t)l * szW1 : 0);
    f16* w2t = W2T   + (hoist ? (size_t)l * szW2 : 0);
    if (!hoist) {
      cvt_qkvw<<<dim3(72, 24), 256, 0, stream>>>(
          wqkv + (size_t)l * 12 * 768 * 192, wq, 0, 0);
      cvt_transpose<<<dim3(24, 24), 256, 0, stream>>>(
          wmsa + (size_t)l * 768 * 768, wms, 768, 768, 0, 0);
      cvt_transpose<<<dim3(96, 24), 256, 0, stream>>>(
          w1 + (size_t)l * 768 * 3072, w1t, 768, 3072, 0, 0);
      cvt_transpose<<<dim3(24, 96), 256, 0, stream>>>(
          w2 + (size_t)l * 3072 * 768, w2t, 3072, 768, 0, 0);
    }

    ln_fwd<<<dim3(MREAL), 256, 0, stream>>>(X, ln1_g + l * 768, ln1_b + l * 768, hbf, hh);
    gemm_k<768, 1><<<dim3(18, 145), 256, 0, stream>>>(
        hh, wq, bqkv + (size_t)l * 2304, nullptr, nullptr, qb, kb, vtb, nullptr, 2304, MREAL);
    attn_k<<<dim3(10, NBATCH * NHEAD), 256, 0, stream>>>(qb, kb, vtb, obuf);
    gemm_k<768, 2><<<dim3(6, 145), 256, 0, stream>>>(
        obuf, wms, bmsa + l * 768, hbf, X, nullptr, nullptr, nullptr, nullptr, 768, MREAL);
    ln2_fwd<<<dim3(MREAL), 256, 0, stream>>>(
        X, ln2_g + l * 768, ln2_b + l * 768, lnm_g + l * 768, lnm_b + l * 768, h2h);
    gemm_k<768, 3><<<dim3(24, 145), 256, 0, stream>>>(
        h2h, w1t, b1 + (size_t)l * 3072, nullptr, nullptr, abuf, nullptr, nullptr, nullptr, 3072, MREAL);
    gemm_k<3072, 2><<<dim3(6, 145), 256, 0, stream>>>(
        abuf, w2t, b2 + l * 768, X, X, nullptr, nullptr, nullptr, nullptr, 768, MREAL);
  }
  head_logits<<<dim3(NBATCH, 4), 256, 0, stream>>>(X, lnf_g, lnf_b, whead, bhead, lgbuf);
  head_soft<<<dim3(NBATCH), 256, 0, stream>>>(lgbuf, out);
}

// Round 7
// 8434.347 us; speedup vs baseline: 1.0034x; 1.0034x over previous
//
#include <hip/hip_runtime.h>

// ---------------- types ----------------
using f16   = _Float16;
using f16x8 = __attribute__((ext_vector_type(8))) _Float16;
using f32x4 = __attribute__((ext_vector_type(4))) float;

#define MPAD  18560          // 145*128, padded token rows
#define MREAL 18464          // 32*577
#define MCONV 18432          // 32*576
#define SEQ   577
#define SPAD  640
#define NHEAD 12
#define NBATCH 32
#define SCALE_ 0.125f        // 1/sqrt(64)

__device__ __forceinline__ void load_lds16(const void* g, void* l) {
  __builtin_amdgcn_global_load_lds(
      (const __attribute__((address_space(1))) void*)g,
      (__attribute__((address_space(3))) void*)l, 16, 0, 0);
}

// ---------------- GEMM: C[M,N] = A[M,K] * Bt[N,K]^T, fused epilogues ----------------
// Round-5 structure verbatim (BK=32, 128^2 tile, 4 waves, m97-style 2-barrier
// loop). Block ordering: bijective XCD chunking (m204) + M-major decode within
// 6-N-tile bands (B band L2-resident). Requires gridDim.x % 6 == 0.
// EPI 0: conv embed (scramble + conv_b + pos_emb -> o32=X)
// EPI 1: qkv scatter (bias; q->o16a [bh][s][e], k->o16b [bh][s][e], v->o16c [bh][e][s])
// EPI 2: bias + raw residual -> o32 (fp32)               (FC2: res = X)
// EPI 3: bias + exact gelu -> o16a (fp16)                (FC1)
// EPI 4: bias + LN1-recomputed residual -> o32 (fp32)    (MSA: h from X,stats)
template<int K, int EPI>
__global__ __launch_bounds__(256) void gemm_k(
    const f16* __restrict__ A, const f16* __restrict__ Bt,
    const float* __restrict__ bias, const float* __restrict__ res,
    float* __restrict__ o32, f16* __restrict__ o16a, f16* __restrict__ o16b,
    f16* __restrict__ o16c, const float* __restrict__ pos,
    const float* __restrict__ lng, const float* __restrict__ lnb,
    const float* __restrict__ stats, int N, int Mreal)
{
  __shared__ __align__(16) f16 As[128*32];
  __shared__ __align__(16) f16 Bs[128*32];
  const int tid = threadIdx.x;
  const int lane = tid & 63, wv = tid >> 6;

  // XCD chunking + band-supertile decode
  const int gx = gridDim.x, gy = gridDim.y;
  const int nwg = gx * gy;
  const int flat = blockIdx.y * gx + blockIdx.x;
  const int xcd = flat & 7;
  const int qq = nwg >> 3, rr = nwg & 7;
  const int p_ = ((xcd < rr) ? xcd * (qq + 1) : rr * (qq + 1) + (xcd - rr) * qq)
                 + (flat >> 3);
  const int bandsz = gy * 6;
  const int band = p_ / bandsz, within = p_ - band * bandsz;
  const int byi = within / 6;
  const int bxi = band * 6 + (within - byi * 6);
  const int bm = byi << 7, bn = bxi << 7;

  const int wm = (wv >> 1) << 6, wn = (wv & 1) << 6;
  const int r16 = lane & 15, g4 = lane >> 4;
  const f32x4 Z4 = {0.f, 0.f, 0.f, 0.f};

  f32x4 acc[4][4];
#pragma unroll
  for (int m = 0; m < 4; ++m)
#pragma unroll
    for (int n = 0; n < 4; ++n) acc[m][n] = Z4;

  const int soff = wv * 1024 + lane * 8;  // halves
  for (int k0 = 0; k0 < K; k0 += 32) {
#pragma unroll
    for (int j = 0; j < 2; ++j) {
      int off = soff + j * 512;
      int row = off >> 5;
      int cs  = (off >> 3) & 3;
      int gc  = cs ^ (row & 3);          // pre-swizzled global source, linear LDS
      load_lds16(A  + (size_t)(bm + row) * K + k0 + gc * 8, As + (wv*2 + j) * 512);
      load_lds16(Bt + (size_t)(bn + row) * K + k0 + gc * 8, Bs + (wv*2 + j) * 512);
    }
    __syncthreads();
    f16x8 af[4], bf[4];
#pragma unroll
    for (int m = 0; m < 4; ++m) {
      int row = wm + m * 16 + r16;
      af[m] = *(const f16x8*)(As + row * 32 + ((g4 ^ (row & 3)) << 3));
    }
#pragma unroll
    for (int n = 0; n < 4; ++n) {
      int row = wn + n * 16 + r16;
      bf[n] = *(const f16x8*)(Bs + row * 32 + ((g4 ^ (row & 3)) << 3));
    }
#pragma unroll
    for (int m = 0; m < 4; ++m)
#pragma unroll
      for (int n = 0; n < 4; ++n)
        acc[m][n] = __builtin_amdgcn_mfma_f32_16x16x32_f16(af[m], bf[n], acc[m][n], 0, 0, 0);
    __syncthreads();
  }

#pragma unroll
  for (int m = 0; m < 4; ++m) {
#pragma unroll
    for (int n = 0; n < 4; ++n) {
#pragma unroll
      for (int r = 0; r < 4; ++r) {
        int grow = bm + wm + m * 16 + g4 * 4 + r;
        int gcol = bn + wn + n * 16 + r16;
        float v = acc[m][n][r];
        if constexpr (EPI == 0) {
          if (grow < Mreal) {
            int b = grow / 576, p = grow - b * 576;
            int i = gcol * 576 + p;               // channel-major flat index
            int sp = i / 768, dd = i - sp * 768;  // faithful .view(b,-1,D) scramble
            o32[((size_t)(b * SEQ + sp + 1)) * 768 + dd] =
                v + bias[gcol] + pos[(size_t)(sp + 1) * 768 + dd];
          }
        } else if constexpr (EPI == 1) {
          if (grow < Mreal) {
            int b = grow / SEQ, s = grow - b * SEQ;
            int hq = gcol / 192, rem = gcol - hq * 192;
            int sel = rem >> 6, e = rem & 63;
            float val = v + bias[gcol];
            int bh = b * NHEAD + hq;
            if (sel == 0)      o16a[((size_t)bh * SPAD + s) * 64 + e] = (f16)val;
            else if (sel == 1) o16b[((size_t)bh * SPAD + s) * 64 + e] = (f16)val;
            else               o16c[((size_t)bh * 64 + e) * SPAD + s] = (f16)val;  // V transposed
          }
        } else if constexpr (EPI == 2) {
          size_t idx = (size_t)grow * N + gcol;
          o32[idx] = v + bias[gcol] + res[idx];
        } else if constexpr (EPI == 4) {
          if (grow < Mreal) {
            size_t idx = (size_t)grow * N + gcol;
            float mu = stats[2 * grow], rs = stats[2 * grow + 1];
            float h = (res[idx] - mu) * rs * lng[gcol] + lnb[gcol];
            o32[idx] = v + bias[gcol] + h;
          }
        } else {
          float val = v + bias[gcol];
          float gl = 0.5f * val * (1.0f + erff(val * 0.70710678f));
          o16a[(size_t)grow * N + gcol] = (f16)gl;
        }
      }
    }
  }
}

// ---------------- block reduce helper ----------------
__device__ __forceinline__ void block_red2(float& a, float& b, float* sm, int tid) {
  __syncthreads();
#pragma unroll
  for (int d = 32; d; d >>= 1) { a += __shfl_down(a, d); b += __shfl_down(b, d); }
  if ((tid & 63) == 0) { int w = tid >> 6; sm[w] = a; sm[w + 4] = b; }
  __syncthreads();
  a = sm[0] + sm[1] + sm[2] + sm[3];
  b = sm[4] + sm[5] + sm[6] + sm[7];
}

// ---------------- LayerNorm (fp32 in -> fp16 out + per-row stats) ----------------
__global__ __launch_bounds__(256) void ln_fwd(const float* __restrict__ X,
    const float* __restrict__ g, const float* __restrict__ bb,
    float* __restrict__ stats, f16* __restrict__ hh)
{
  int row = blockIdx.x, tid = threadIdx.x;
  const float* x = X + (size_t)row * 768;
  float v0 = x[tid], v1 = x[tid + 256], v2 = x[tid + 512];
  float s = v0 + v1 + v2, s2 = v0*v0 + v1*v1 + v2*v2;
  __shared__ float sm[8];
  block_red2(s, s2, sm, tid);
  float mu = s * (1.f/768.f);
  float var = s2 * (1.f/768.f) - mu * mu;
  float rs = rsqrtf(var + 1e-5f);
  if (tid == 0) { stats[2 * row] = mu; stats[2 * row + 1] = rs; }
  size_t base = (size_t)row * 768;
  hh[base + tid      ] = (f16)((v0 - mu) * rs * g[tid      ] + bb[tid      ]);
  hh[base + tid + 256] = (f16)((v1 - mu) * rs * g[tid + 256] + bb[tid + 256]);
  hh[base + tid + 512] = (f16)((v2 - mu) * rs * g[tid + 512] + bb[tid + 512]);
}

// ---------------- Double LayerNorm (LN(LN(x))) -> fp16 ----------------
__global__ __launch_bounds__(256) void ln2_fwd(const float* __restrict__ X,
    const float* __restrict__ g2, const float* __restrict__ bb2,
    const float* __restrict__ gm, const float* __restrict__ bbm,
    f16* __restrict__ hh)
{
  int row = blockIdx.x, tid = threadIdx.x;
  const float* x = X + (size_t)row * 768;
  float v0 = x[tid], v1 = x[tid + 256], v2 = x[tid + 512];
  float s = v0 + v1 + v2, s2 = v0*v0 + v1*v1 + v2*v2;
  __shared__ float sm[8];
  block_red2(s, s2, sm, tid);
  float mu = s * (1.f/768.f), var = s2 * (1.f/768.f) - mu * mu;
  float rs = rsqrtf(var + 1e-5f);
  float y0 = (v0 - mu) * rs * g2[tid      ] + bb2[tid      ];
  float y1 = (v1 - mu) * rs * g2[tid + 256] + bb2[tid + 256];
  float y2 = (v2 - mu) * rs * g2[tid + 512] + bb2[tid + 512];
  s = y0 + y1 + y2; s2 = y0*y0 + y1*y1 + y2*y2;
  block_red2(s, s2, sm, tid);
  mu = s * (1.f/768.f); var = s2 * (1.f/768.f) - mu * mu;
  rs = rsqrtf(var + 1e-5f);
  size_t base = (size_t)row * 768;
  hh[base + tid      ] = (f16)((y0 - mu) * rs * gm[tid      ] + bbm[tid      ]);
  hh[base + tid + 256] = (f16)((y1 - mu) * rs * gm[tid + 256] + bbm[tid + 256]);
  hh[base + tid + 512] = (f16)((y2 - mu) * rs * gm[tid + 512] + bbm[tid + 512]);
}

// ---------------- flash attention (64 q-rows / block, online softmax, defer-max) ----------------
__global__ __launch_bounds__(256) void attn_k(const f16* __restrict__ qbuf,
    const f16* __restrict__ kbuf, const f16* __restrict__ vtbuf,
    f16* __restrict__ obuf)
{
  const int bh = blockIdx.y;
  const int b = bh / NHEAD, hd = bh - b * NHEAD;
  const int s0 = blockIdx.x << 6;
  const int tid = threadIdx.x, lane = tid & 63, wv = tid >> 6;
  const int r16 = lane & 15, g4 = lane >> 4;
  const f16* Q  = qbuf  + (size_t)bh * SPAD * 64;
  const f16* Kg = kbuf  + (size_t)bh * SPAD * 64;
  const f16* Vg = vtbuf + (size_t)bh * 64 * SPAD;
  __shared__ __align__(16) f16 Kt[64 * 64];
  __shared__ __align__(16) f16 Vt[64 * 64];
  __shared__ __align__(16) f16 Pw[4][16][72];
  const f32x4 Z4 = {0.f, 0.f, 0.f, 0.f};

  f16x8 qf[2];
  {
    const f16* qr = Q + (size_t)(s0 + wv * 16 + r16) * 64;
    qf[0] = *(const f16x8*)(qr + g4 * 8);
    qf[1] = *(const f16x8*)(qr + 32 + g4 * 8);
  }
  float m_run[4] = {-1e30f, -1e30f, -1e30f, -1e30f};
  float l_run[4] = {0.f, 0.f, 0.f, 0.f};
  f32x4 o_acc[4];
#pragma unroll
  for (int n = 0; n < 4; ++n) o_acc[n] = Z4;

  for (int kt = 0; kt < SPAD; kt += 64) {
#pragma unroll
    for (int j = 0; j < 2; ++j) {
      int off = (wv * 2 + j) * 1024 + lane * 16;  // bytes
      int row = off >> 7;
      int cs  = (off >> 4) & 7;
      int gc  = cs ^ (row & 7);                   // 8-chunk XOR swizzle
      load_lds16(Kg + (size_t)(kt + row) * 64 + gc * 8, (void*)((char*)Kt + (wv*2 + j) * 1024));
      load_lds16(Vg + (size_t)row * SPAD + kt + gc * 8, (void*)((char*)Vt + (wv*2 + j) * 1024));
    }
    __syncthreads();

    f32x4 sa[4];
#pragma unroll
    for (int n = 0; n < 4; ++n) sa[n] = Z4;
#pragma unroll
    for (int n = 0; n < 4; ++n) {
      int krow = n * 16 + r16;
#pragma unroll
      for (int kc = 0; kc < 2; ++kc) {
        f16x8 kf = *(const f16x8*)(Kt + krow * 64 + (((kc * 4 + g4) ^ (krow & 7)) << 3));
        sa[n] = __builtin_amdgcn_mfma_f32_16x16x32_f16(qf[kc], kf, sa[n], 0, 0, 0);
      }
    }
#pragma unroll
    for (int r = 0; r < 4; ++r) {
      float mx = -1e30f;
#pragma unroll
      for (int n = 0; n < 4; ++n) {
        int key = kt + n * 16 + r16;
        float sv = (key < SEQ) ? sa[n][r] * SCALE_ : -1e30f;
        sa[n][r] = sv;
        mx = fmaxf(mx, sv);
      }
#pragma unroll
      for (int d = 1; d < 16; d <<= 1) mx = fmaxf(mx, __shfl_xor(mx, d));
      // defer-max (T13): only rescale when some row's max grew by > 8
      if (!__all(mx - m_run[r] <= 8.f)) {
        float mnew = fmaxf(m_run[r], mx);
        float alpha = __expf(m_run[r] - mnew);
        m_run[r] = mnew;
        l_run[r] *= alpha;
#pragma unroll
        for (int n = 0; n < 4; ++n) o_acc[n][r] *= alpha;
      }
      float ssum = 0.f;
#pragma unroll
      for (int n = 0; n < 4; ++n) {
        float p = __expf(sa[n][r] - m_run[r]);   // bounded by e^8
        ssum += p;
        Pw[wv][g4 * 4 + r][n * 16 + r16] = (f16)p;
      }
#pragma unroll
      for (int d = 1; d < 16; d <<= 1) ssum += __shfl_xor(ssum, d);
      l_run[r] += ssum;
    }
    f16x8 pf[2];
    pf[0] = *(const f16x8*)(&Pw[wv][r16][g4 * 8]);
    pf[1] = *(const f16x8*)(&Pw[wv][r16][32 + g4 * 8]);
#pragma unroll
    for (int n = 0; n < 4; ++n) {
      int erow = n * 16 + r16;
#pragma unroll
      for (int kc = 0; kc < 2; ++kc) {
        f16x8 vf = *(const f16x8*)(Vt + erow * 64 + (((kc * 4 + g4) ^ (erow & 7)) << 3));
        o_acc[n] = __builtin_amdgcn_mfma_f32_16x16x32_f16(pf[kc], vf, o_acc[n], 0, 0, 0);
      }
    }
    __syncthreads();
  }
  float inv[4];
#pragma unroll
  for (int r = 0; r < 4; ++r) inv[r] = 1.f / l_run[r];
#pragma unroll
  for (int n = 0; n < 4; ++n)
#pragma unroll
    for (int r = 0; r < 4; ++r) {
      int s = s0 + wv * 16 + g4 * 4 + r;
      if (s < SEQ)
        obuf[((size_t)(b * SEQ + s)) * 768 + hd * 64 + n * 16 + r16] =
            (f16)(o_acc[n][r] * inv[r]);
    }
}

// ---------------- weight converts (blockIdx.z = layer) ----------------
__global__ __launch_bounds__(256) void cvt_transpose(const float* __restrict__ in,
    f16* __restrict__ out, int K, int N, size_t ls_in, size_t ls_out)
{
  in  += (size_t)blockIdx.z * ls_in;
  out += (size_t)blockIdx.z * ls_out;
  __shared__ float t[32][33];
  int n0 = blockIdx.x << 5, k0 = blockIdx.y << 5;
  int tx = threadIdx.x & 31, ty = threadIdx.x >> 5;
#pragma unroll
  for (int i = 0; i < 4; ++i) t[ty + 8*i][tx] = in[(size_t)(k0 + ty + 8*i) * N + n0 + tx];
  __syncthreads();
#pragma unroll
  for (int i = 0; i < 4; ++i) out[(size_t)(n0 + ty + 8*i) * K + k0 + tx] = (f16)t[tx][ty + 8*i];
}

__global__ __launch_bounds__(256) void cvt_qkvw(const float* __restrict__ in,
    f16* __restrict__ out, size_t ls_in, size_t ls_out)
{
  in  += (size_t)blockIdx.z * ls_in;
  out += (size_t)blockIdx.z * ls_out;
  __shared__ float t[32][33];
  int n0 = blockIdx.x << 5, k0 = blockIdx.y << 5;
  int tx = threadIdx.x & 31, ty = threadIdx.x >> 5;
  int hq = n0 / 192, r0 = n0 - hq * 192;
#pragma unroll
  for (int i = 0; i < 4; ++i)
    t[ty + 8*i][tx] = in[(size_t)hq * 147456 + (size_t)(k0 + ty + 8*i) * 192 + r0 + tx];
  __syncthreads();
#pragma unroll
  for (int i = 0; i < 4; ++i) out[(size_t)(n0 + ty + 8*i) * 768 + k0 + tx] = (f16)t[tx][ty + 8*i];
}

__global__ __launch_bounds__(256) void cvt_plain(const float* __restrict__ in,
    f16* __restrict__ out, int n)
{
  int i = blockIdx.x * 1024 + threadIdx.x;
#pragma unroll
  for (int j = 0; j < 4; ++j) { int idx = i + j * 256; if (idx < n) out[idx] = (f16)in[idx]; }
}

__global__ __launch_bounds__(256) void zero_vpad(f16* __restrict__ vtb) {
  int bh = blockIdx.x;
  for (int idx = threadIdx.x; idx < 64 * (SPAD - SEQ); idx += 256) {
    int e = idx / (SPAD - SEQ), s = SEQ + idx - e * (SPAD - SEQ);
    vtb[((size_t)bh * 64 + e) * SPAD + s] = (f16)0.f;
  }
}

// ---------------- patchify (im2col) & cls ----------------
__global__ __launch_bounds__(256) void im2col_k(const float* __restrict__ x, f16* __restrict__ out) {
  int row = blockIdx.x;
  int b = row / 576, p = row - b * 576;
  int py = p / 24, px = p - py * 24;
  int tid = threadIdx.x;
#pragma unroll
  for (int j = 0; j < 3; ++j) {
    int k = tid + j * 256;
    int c = k >> 8, rem = k & 255;
    int iy = rem >> 4, ix = rem & 15;
    out[(size_t)row * 768 + k] =
        (f16)x[(((size_t)(b * 3 + c)) * 384 + py * 16 + iy) * 384 + px * 16 + ix];
  }
}

__global__ __launch_bounds__(256) void cls_k(const float* __restrict__ ct,
    const float* __restrict__ pos, float* __restrict__ X)
{
  int b = blockIdx.x, tid = threadIdx.x;
#pragma unroll
  for (int j = 0; j < 3; ++j) {
    int d0 = tid + j * 256;
    X[((size_t)b * SEQ) * 768 + d0] = ct[d0] + pos[d0];
  }
}

// ---------------- classifier head: logits (grid 32 x 4) + softmax (grid 32) ----------------
__global__ __launch_bounds__(256) void head_logits(const float* __restrict__ X,
    const float* __restrict__ g, const float* __restrict__ bb,
    const float* __restrict__ W, const float* __restrict__ bhd,
    float* __restrict__ lg)
{
  int b = blockIdx.x, tid = threadIdx.x;
  const float* x = X + (size_t)(b * SEQ) * 768;
  float v0 = x[tid], v1 = x[tid + 256], v2 = x[tid + 512];
  float s = v0 + v1 + v2, s2 = v0*v0 + v1*v1 + v2*v2;
  __shared__ float sm[8];
  block_red2(s, s2, sm, tid);
  float mu = s * (1.f/768.f), var = s2 * (1.f/768.f) - mu * mu;
  float rs = rsqrtf(var + 1e-5f);
  __shared__ float y[768];
  y[tid      ] = (v0 - mu) * rs * g[tid      ] + bb[tid      ];
  y[tid + 256] = (v1 - mu) * rs * g[tid + 256] + bb[tid + 256];
  y[tid + 512] = (v2 - mu) * rs * g[tid + 512] + bb[tid + 512];
  __syncthreads();
  int c = blockIdx.y * 250 + tid;
  if (tid < 250) {
    float a0 = 0.f, a1 = 0.f, a2 = 0.f, a3 = 0.f;
#pragma unroll 4
    for (int d = 0; d < 768; d += 4) {
      a0 = fmaf(y[d    ], W[(size_t)(d    ) * 1000 + c], a0);
      a1 = fmaf(y[d + 1], W[(size_t)(d + 1) * 1000 + c], a1);
      a2 = fmaf(y[d + 2], W[(size_t)(d + 2) * 1000 + c], a2);
      a3 = fmaf(y[d + 3], W[(size_t)(d + 3) * 1000 + c], a3);
    }
    lg[(size_t)b * 1000 + c] = (a0 + a1) + (a2 + a3) + bhd[c];
  }
}

__global__ __launch_bounds__(256) void head_soft(const float* __restrict__ lg,
    float* __restrict__ out)
{
  int b = blockIdx.x, tid = threadIdx.x;
  __shared__ float sm[8];
  float v[4], mx = -1e30f;
#pragma unroll
  for (int j = 0; j < 4; ++j) {
    int c = tid + j * 256;
    v[j] = (c < 1000) ? lg[(size_t)b * 1000 + c] : -1e30f;
    mx = fmaxf(mx, v[j]);
  }
#pragma unroll
  for (int d = 32; d; d >>= 1) mx = fmaxf(mx, __shfl_down(mx, d));
  if ((tid & 63) == 0) sm[tid >> 6] = mx;
  __syncthreads();
  mx = fmaxf(fmaxf(sm[0], sm[1]), fmaxf(sm[2], sm[3]));
  float se = 0.f, ex[4];
#pragma unroll
  for (int j = 0; j < 4; ++j) {
    int c = tid + j * 256;
    ex[j] = (c < 1000) ? __expf(v[j] - mx) : 0.f;
    se += ex[j];
  }
  __syncthreads();
#pragma unroll
  for (int d = 32; d; d >>= 1) se += __shfl_down(se, d);
  if ((tid & 63) == 0) sm[tid >> 6] = se;
  __syncthreads();
  se = sm[0] + sm[1] + sm[2] + sm[3];
  float inv = 1.f / se;
#pragma unroll
  for (int j = 0; j < 4; ++j) {
    int c = tid + j * 256;
    if (c < 1000) out[(size_t)b * 1000 + c] = ex[j] * inv;
  }
}

// ---------------- launcher ----------------
extern "C" void kernel_launch(void* const* d_in, const int* in_sizes, int n_in,
                              void* d_out, int out_size, void* d_ws, size_t ws_size,
                              hipStream_t stream)
{
  (void)in_sizes; (void)n_in; (void)out_size;
  const float* x      = (const float*)d_in[0];
  const float* conv_w = (const float*)d_in[1];
  const float* conv_b = (const float*)d_in[2];
  const float* cls_t  = (const float*)d_in[3];
  const float* pos    = (const float*)d_in[4];
  const float* ln1_g  = (const float*)d_in[5];
  const float* ln1_b  = (const float*)d_in[6];
  const float* wqkv   = (const float*)d_in[7];
  const float* bqkv   = (const float*)d_in[8];
  const float* wmsa   = (const float*)d_in[9];
  const float* bmsa   = (const float*)d_in[10];
  const float* ln2_g  = (const float*)d_in[11];
  const float* ln2_b  = (const float*)d_in[12];
  const float* lnm_g  = (const float*)d_in[13];
  const float* lnm_b  = (const float*)d_in[14];
  const float* w1     = (const float*)d_in[15];
  const float* b1     = (const float*)d_in[16];
  const float* w2     = (const float*)d_in[17];
  const float* b2     = (const float*)d_in[18];
  const float* lnf_g  = (const float*)d_in[19];
  const float* lnf_b  = (const float*)d_in[20];
  const float* whead  = (const float*)d_in[21];
  const float* bhead  = (const float*)d_in[22];
  float* out = (float*)d_out;

  const size_t szQ  = (size_t)2304 * 768;
  const size_t szM  = (size_t)768 * 768;
  const size_t szW1 = (size_t)3072 * 768;
  const size_t szW2 = (size_t)768 * 3072;
  const size_t fixed_bytes =
      (size_t)MPAD * 768 * 4 + (size_t)MPAD * 8 + 32 * 1000 * 4 +
      (size_t)MPAD * 768 * 2 +
      (size_t)MPAD * 3072 * 2 + 3 * ((size_t)NBATCH * NHEAD * SPAD * 64 * 2) +
      (size_t)768 * 768 * 2 /*WcT*/ + 16 * 256 /*align slack*/;
  const bool hoist =
      ws_size >= fixed_bytes + 12 * (szQ + szM + szW1 + szW2) * 2 + 8 * 256;
  const int LW = hoist ? 12 : 1;

  char* wsp = (char*)d_ws;
  size_t off = 0;
  auto alloc = [&](size_t bytes) {
    char* p = wsp + off; off += (bytes + 255) & ~(size_t)255; return p;
  };
  float* X    = (float*)alloc((size_t)MPAD * 768 * 4);
  float* stats= (float*)alloc((size_t)MPAD * 8);
  float* lgbuf= (float*)alloc((size_t)32 * 1000 * 4);
  f16*   hh   = (f16*)  alloc((size_t)MPAD * 768 * 2);
  f16*   abuf = (f16*)  alloc((size_t)MPAD * 3072 * 2);
  f16*   qb   = (f16*)  alloc((size_t)NBATCH * NHEAD * SPAD * 64 * 2);
  f16*   kb   = (f16*)  alloc((size_t)NBATCH * NHEAD * SPAD * 64 * 2);
  f16*   vtb  = (f16*)  alloc((size_t)NBATCH * NHEAD * SPAD * 64 * 2);
  f16*   WcT  = (f16*)  alloc((size_t)768 * 768 * 2);
  f16*   WqkvT= (f16*)  alloc(LW * szQ  * 2);
  f16*   WmsaT= (f16*)  alloc(LW * szM  * 2);
  f16*   W1T  = (f16*)  alloc(LW * szW1 * 2);
  f16*   W2T  = (f16*)  alloc(LW * szW2 * 2);
  f16*   obuf   = abuf;   // alias: attn out, consumed by MSA before FC1 writes abuf
  f16*   patchA = abuf;   // alias: im2col buffer, consumed by conv GEMM pre-loop
  f16*   h2h    = hh;     // alias: hh dead after QKV GEMM each layer
  if (ws_size < off) return;  // workspace too small: bail (bench will flag)

  zero_vpad<<<dim3(NBATCH * NHEAD), 256, 0, stream>>>(vtb);
  cvt_plain<<<dim3((768 * 768 + 1023) / 1024), 256, 0, stream>>>(conv_w, WcT, 768 * 768);
  if (hoist) {  // convert all 12 layers' weights up front
    cvt_qkvw<<<dim3(72, 24, 12), 256, 0, stream>>>(wqkv, WqkvT, (size_t)12*768*192, szQ);
    cvt_transpose<<<dim3(24, 24, 12), 256, 0, stream>>>(wmsa, WmsaT, 768, 768, szM, szM);
    cvt_transpose<<<dim3(96, 24, 12), 256, 0, stream>>>(w1, W1T, 768, 3072, szW1, szW1);
    cvt_transpose<<<dim3(24, 96, 12), 256, 0, stream>>>(w2, W2T, 3072, 768, szW2, szW2);
  }
  im2col_k<<<dim3(MCONV), 256, 0, stream>>>(x, patchA);
  gemm_k<768, 0><<<dim3(6, 144), 256, 0, stream>>>(
      patchA, WcT, conv_b, nullptr, X, nullptr, nullptr, nullptr, pos,
      nullptr, nullptr, nullptr, 768, MCONV);
  cls_k<<<dim3(NBATCH), 256, 0, stream>>>(cls_t, pos, X);

  for (int l = 0; l < 12; ++l) {
    f16* wq  = WqkvT + (hoist ? (size_t)l * szQ  : 0);
    f16* wms = WmsaT + (hoist ? (size_t)l * szM  : 0);
    f16* w1t = W1T   + (hoist ? (size_t)l * szW1 : 0);
    f16* w2t = W2T   + (hoist ? (size_t)l * szW2 : 0);
    if (!hoist) {
      cvt_qkvw<<<dim3(72, 24), 256, 0, stream>>>(
          wqkv + (size_t)l * 12 * 768 * 192, wq, 0, 0);
      cvt_transpose<<<dim3(24, 24), 256, 0, stream>>>(
          wmsa + (size_t)l * 768 * 768, wms, 768, 768, 0, 0);
      cvt_transpose<<<dim3(96, 24), 256, 0, stream>>>(
          w1 + (size_t)l * 768 * 3072, w1t, 768, 3072, 0, 0);
      cvt_transpose<<<dim3(24, 96), 256, 0, stream>>>(
          w2 + (size_t)l * 3072 * 768, w2t, 3072, 768, 0, 0);
    }

    ln_fwd<<<dim3(MREAL), 256, 0, stream>>>(X, ln1_g + l * 768, ln1_b + l * 768, stats, hh);
    gemm_k<768, 1><<<dim3(18, 145), 256, 0, stream>>>(
        hh, wq, bqkv + (size_t)l * 2304, nullptr, nullptr, qb, kb, vtb, nullptr,
        nullptr, nullptr, nullptr, 2304, MREAL);
    attn_k<<<dim3(10, NBATCH * NHEAD), 256, 0, stream>>>(qb, kb, vtb, obuf);
    gemm_k<768, 4><<<dim3(6, 145), 256, 0, stream>>>(
        obuf, wms, bmsa + l * 768, X, X, nullptr, nullptr, nullptr, nullptr,
        ln1_g + l * 768, ln1_b + l * 768, stats, 768, MREAL);
    ln2_fwd<<<dim3(MREAL), 256, 0, stream>>>(
        X, ln2_g + l * 768, ln2_b + l * 768, lnm_g + l * 768, lnm_b + l * 768, h2h);
    gemm_k<768, 3><<<dim3(24, 145), 256, 0, stream>>>(
        h2h, w1t, b1 + (size_t)l * 3072, nullptr, nullptr, abuf, nullptr, nullptr, nullptr,
        nullptr, nullptr, nullptr, 3072, MREAL);
    gemm_k<3072, 2><<<dim3(6, 145), 256, 0, stream>>>(
        abuf, w2t, b2 + l * 768, X, X, nullptr, nullptr, nullptr, nullptr,
        nullptr, nullptr, nullptr, 768, MREAL);
  }
  head_logits<<<dim3(NBATCH, 4), 256, 0, stream>>>(X, lnf_g, lnf_b, whead, bhead, lgbuf);
  head_soft<<<dim3(NBATCH), 256, 0, stream>>>(lgbuf, out);
}

// Round 8
// 8202.643 us; speedup vs baseline: 1.0317x; 1.0282x over previous
//
#include <hip/hip_runtime.h>

// ---------------- types ----------------
using f16   = _Float16;
using f16x8 = __attribute__((ext_vector_type(8))) _Float16;
using f32x4 = __attribute__((ext_vector_type(4))) float;

#define MPAD  18560          // 145*128, padded token rows
#define MREAL 18464          // 32*577
#define MCONV 18432          // 32*576
#define SEQ   577
#define SPAD  640
#define NHEAD 12
#define NBATCH 32
#define SCALE_ 0.125f        // 1/sqrt(64)

__device__ __forceinline__ void load_lds16(const void* g, void* l) {
  __builtin_amdgcn_global_load_lds(
      (const __attribute__((address_space(1))) void*)g,
      (__attribute__((address_space(3))) void*)l, 16, 0, 0);
}

// ---------------- GEMM: C[M,N] = A[M,K] * Bt[N,K]^T, fused epilogues ----------------
// BK=64 conflict-free LDS layout (128B rows = 32 banks; reads are 2-way max =
// free, round-3 verified 0 conflicts) + m97-style single-buffer 2-barrier loop.
// Staging: 8 x 1KB wave-linear global_load_lds; global chunk pre-swizzle
// gc = cs ^ (row&7); reads use slot ((ks*4+g4) ^ (row&7)).
// Block ordering: bijective XCD chunking (m204) + M-major decode within
// 6-N-tile bands (B band L2-resident). Requires gridDim.x % 6 == 0.
// EPI 0: conv embed (scramble + conv_b + pos_emb -> o32=X)
// EPI 1: qkv scatter (bias; q->o16a [bh][s][e], k->o16b [bh][s][e], v->o16c [bh][e][s])
// EPI 2: bias + raw residual -> o32 (fp32)               (FC2: res = X)
// EPI 3: bias + exact gelu -> o16a (fp16)                (FC1)
// EPI 4: bias + LN1-recomputed residual -> o32 (fp32)    (MSA: h from X,stats)
template<int K, int EPI>
__global__ __launch_bounds__(256) void gemm_k(
    const f16* __restrict__ A, const f16* __restrict__ Bt,
    const float* __restrict__ bias, const float* __restrict__ res,
    float* __restrict__ o32, f16* __restrict__ o16a, f16* __restrict__ o16b,
    f16* __restrict__ o16c, const float* __restrict__ pos,
    const float* __restrict__ lng, const float* __restrict__ lnb,
    const float* __restrict__ stats, int N, int Mreal)
{
  static_assert(K % 64 == 0, "BK=64");
  __shared__ __align__(16) f16 As[128 * 64];
  __shared__ __align__(16) f16 Bs[128 * 64];
  const int tid = threadIdx.x;
  const int lane = tid & 63, wv = tid >> 6;

  // XCD chunking + band-supertile decode
  const int gx = gridDim.x, gy = gridDim.y;
  const int nwg = gx * gy;
  const int flat = blockIdx.y * gx + blockIdx.x;
  const int xcd = flat & 7;
  const int qq = nwg >> 3, rr = nwg & 7;
  const int p_ = ((xcd < rr) ? xcd * (qq + 1) : rr * (qq + 1) + (xcd - rr) * qq)
                 + (flat >> 3);
  const int bandsz = gy * 6;
  const int band = p_ / bandsz, within = p_ - band * bandsz;
  const int byi = within / 6;
  const int bxi = band * 6 + (within - byi * 6);
  const int bm = byi << 7, bn = bxi << 7;

  const int wm = (wv >> 1) << 6, wn = (wv & 1) << 6;
  const int r16 = lane & 15, g4 = lane >> 4;
  const f32x4 Z4 = {0.f, 0.f, 0.f, 0.f};

  f32x4 acc[4][4];
#pragma unroll
  for (int m = 0; m < 4; ++m)
#pragma unroll
    for (int n = 0; n < 4; ++n) acc[m][n] = Z4;

  // staging: each gload_lds = 64 lanes x 16B = 8 rows x 128B, wave-linear dest.
  // lane -> (row_local = lane>>3, slot cs = lane&7), global chunk = cs ^ row_local.
  const int srow = lane >> 3;          // 0..7
  const int sgc  = (lane & 7) ^ srow;  // pre-swizzled global chunk
  const f16* Agp = A  + (size_t)(bm + srow) * K + sgc * 8;
  const f16* Bgp = Bt + (size_t)(bn + srow) * K + sgc * 8;

  for (int k0 = 0; k0 < K; k0 += 64) {
#pragma unroll
    for (int j = 0; j < 4; ++j) {
      const size_t roff = (size_t)((wv * 4 + j) * 8) * K + k0;
      load_lds16(Agp + roff, As + (wv * 4 + j) * 512);
      load_lds16(Bgp + roff, Bs + (wv * 4 + j) * 512);
    }
    __syncthreads();
#pragma unroll
    for (int ks = 0; ks < 2; ++ks) {
      f16x8 af[4], bf[4];
#pragma unroll
      for (int m = 0; m < 4; ++m) {
        int row = wm + m * 16 + r16;
        af[m] = *(const f16x8*)(As + row * 64 + ((((ks << 2) | g4) ^ (row & 7)) << 3));
      }
#pragma unroll
      for (int n = 0; n < 4; ++n) {
        int row = wn + n * 16 + r16;
        bf[n] = *(const f16x8*)(Bs + row * 64 + ((((ks << 2) | g4) ^ (row & 7)) << 3));
      }
#pragma unroll
      for (int m = 0; m < 4; ++m)
#pragma unroll
        for (int n = 0; n < 4; ++n)
          acc[m][n] = __builtin_amdgcn_mfma_f32_16x16x32_f16(af[m], bf[n], acc[m][n], 0, 0, 0);
    }
    __syncthreads();
  }

#pragma unroll
  for (int m = 0; m < 4; ++m) {
#pragma unroll
    for (int n = 0; n < 4; ++n) {
#pragma unroll
      for (int r = 0; r < 4; ++r) {
        int grow = bm + wm + m * 16 + g4 * 4 + r;
        int gcol = bn + wn + n * 16 + r16;
        float v = acc[m][n][r];
        if constexpr (EPI == 0) {
          if (grow < Mreal) {
            int b = grow / 576, p = grow - b * 576;
            int i = gcol * 576 + p;               // channel-major flat index
            int sp = i / 768, dd = i - sp * 768;  // faithful .view(b,-1,D) scramble
            o32[((size_t)(b * SEQ + sp + 1)) * 768 + dd] =
                v + bias[gcol] + pos[(size_t)(sp + 1) * 768 + dd];
          }
        } else if constexpr (EPI == 1) {
          if (grow < Mreal) {
            int b = grow / SEQ, s = grow - b * SEQ;
            int hq = gcol / 192, rem = gcol - hq * 192;
            int sel = rem >> 6, e = rem & 63;
            float val = v + bias[gcol];
            int bh = b * NHEAD + hq;
            if (sel == 0)      o16a[((size_t)bh * SPAD + s) * 64 + e] = (f16)val;
            else if (sel == 1) o16b[((size_t)bh * SPAD + s) * 64 + e] = (f16)val;
            else               o16c[((size_t)bh * 64 + e) * SPAD + s] = (f16)val;  // V transposed
          }
        } else if constexpr (EPI == 2) {
          size_t idx = (size_t)grow * N + gcol;
          o32[idx] = v + bias[gcol] + res[idx];
        } else if constexpr (EPI == 4) {
          if (grow < Mreal) {
            size_t idx = (size_t)grow * N + gcol;
            float mu = stats[2 * grow], rs = stats[2 * grow + 1];
            float h = (res[idx] - mu) * rs * lng[gcol] + lnb[gcol];
            o32[idx] = v + bias[gcol] + h;
          }
        } else {
          float val = v + bias[gcol];
          float gl = 0.5f * val * (1.0f + erff(val * 0.70710678f));
          o16a[(size_t)grow * N + gcol] = (f16)gl;
        }
      }
    }
  }
}

// ---------------- block reduce helper ----------------
__device__ __forceinline__ void block_red2(float& a, float& b, float* sm, int tid) {
  __syncthreads();
#pragma unroll
  for (int d = 32; d; d >>= 1) { a += __shfl_down(a, d); b += __shfl_down(b, d); }
  if ((tid & 63) == 0) { int w = tid >> 6; sm[w] = a; sm[w + 4] = b; }
  __syncthreads();
  a = sm[0] + sm[1] + sm[2] + sm[3];
  b = sm[4] + sm[5] + sm[6] + sm[7];
}

// ---------------- LayerNorm (fp32 in -> fp16 out + per-row stats) ----------------
__global__ __launch_bounds__(256) void ln_fwd(const float* __restrict__ X,
    const float* __restrict__ g, const float* __restrict__ bb,
    float* __restrict__ stats, f16* __restrict__ hh)
{
  int row = blockIdx.x, tid = threadIdx.x;
  const float* x = X + (size_t)row * 768;
  float v0 = x[tid], v1 = x[tid + 256], v2 = x[tid + 512];
  float s = v0 + v1 + v2, s2 = v0*v0 + v1*v1 + v2*v2;
  __shared__ float sm[8];
  block_red2(s, s2, sm, tid);
  float mu = s * (1.f/768.f);
  float var = s2 * (1.f/768.f) - mu * mu;
  float rs = rsqrtf(var + 1e-5f);
  if (tid == 0) { stats[2 * row] = mu; stats[2 * row + 1] = rs; }
  size_t base = (size_t)row * 768;
  hh[base + tid      ] = (f16)((v0 - mu) * rs * g[tid      ] + bb[tid      ]);
  hh[base + tid + 256] = (f16)((v1 - mu) * rs * g[tid + 256] + bb[tid + 256]);
  hh[base + tid + 512] = (f16)((v2 - mu) * rs * g[tid + 512] + bb[tid + 512]);
}

// ---------------- Double LayerNorm (LN(LN(x))) -> fp16 ----------------
__global__ __launch_bounds__(256) void ln2_fwd(const float* __restrict__ X,
    const float* __restrict__ g2, const float* __restrict__ bb2,
    const float* __restrict__ gm, const float* __restrict__ bbm,
    f16* __restrict__ hh)
{
  int row = blockIdx.x, tid = threadIdx.x;
  const float* x = X + (size_t)row * 768;
  float v0 = x[tid], v1 = x[tid + 256], v2 = x[tid + 512];
  float s = v0 + v1 + v2, s2 = v0*v0 + v1*v1 + v2*v2;
  __shared__ float sm[8];
  block_red2(s, s2, sm, tid);
  float mu = s * (1.f/768.f), var = s2 * (1.f/768.f) - mu * mu;
  float rs = rsqrtf(var + 1e-5f);
  float y0 = (v0 - mu) * rs * g2[tid      ] + bb2[tid      ];
  float y1 = (v1 - mu) * rs * g2[tid + 256] + bb2[tid + 256];
  float y2 = (v2 - mu) * rs * g2[tid + 512] + bb2[tid + 512];
  s = y0 + y1 + y2; s2 = y0*y0 + y1*y1 + y2*y2;
  block_red2(s, s2, sm, tid);
  mu = s * (1.f/768.f); var = s2 * (1.f/768.f) - mu * mu;
  rs = rsqrtf(var + 1e-5f);
  size_t base = (size_t)row * 768;
  hh[base + tid      ] = (f16)((y0 - mu) * rs * gm[tid      ] + bbm[tid      ]);
  hh[base + tid + 256] = (f16)((y1 - mu) * rs * gm[tid + 256] + bbm[tid + 256]);
  hh[base + tid + 512] = (f16)((y2 - mu) * rs * gm[tid + 512] + bbm[tid + 512]);
}

// ---------------- flash attention (64 q-rows / block, online softmax, defer-max) ----------------
__global__ __launch_bounds__(256) void attn_k(const f16* __restrict__ qbuf,
    const f16* __restrict__ kbuf, const f16* __restrict__ vtbuf,
    f16* __restrict__ obuf)
{
  const int bh = blockIdx.y;
  const int b = bh / NHEAD, hd = bh - b * NHEAD;
  const int s0 = blockIdx.x << 6;
  const int tid = threadIdx.x, lane = tid & 63, wv = tid >> 6;
  const int r16 = lane & 15, g4 = lane >> 4;
  const f16* Q  = qbuf  + (size_t)bh * SPAD * 64;
  const f16* Kg = kbuf  + (size_t)bh * SPAD * 64;
  const f16* Vg = vtbuf + (size_t)bh * 64 * SPAD;
  __shared__ __align__(16) f16 Kt[64 * 64];
  __shared__ __align__(16) f16 Vt[64 * 64];
  __shared__ __align__(16) f16 Pw[4][16][72];
  const f32x4 Z4 = {0.f, 0.f, 0.f, 0.f};

  f16x8 qf[2];
  {
    const f16* qr = Q + (size_t)(s0 + wv * 16 + r16) * 64;
    qf[0] = *(const f16x8*)(qr + g4 * 8);
    qf[1] = *(const f16x8*)(qr + 32 + g4 * 8);
  }
  float m_run[4] = {-1e30f, -1e30f, -1e30f, -1e30f};
  float l_run[4] = {0.f, 0.f, 0.f, 0.f};
  f32x4 o_acc[4];
#pragma unroll
  for (int n = 0; n < 4; ++n) o_acc[n] = Z4;

  for (int kt = 0; kt < SPAD; kt += 64) {
#pragma unroll
    for (int j = 0; j < 2; ++j) {
      int off = (wv * 2 + j) * 1024 + lane * 16;  // bytes
      int row = off >> 7;
      int cs  = (off >> 4) & 7;
      int gc  = cs ^ (row & 7);                   // 8-chunk XOR swizzle
      load_lds16(Kg + (size_t)(kt + row) * 64 + gc * 8, (void*)((char*)Kt + (wv*2 + j) * 1024));
      load_lds16(Vg + (size_t)row * SPAD + kt + gc * 8, (void*)((char*)Vt + (wv*2 + j) * 1024));
    }
    __syncthreads();

    f32x4 sa[4];
#pragma unroll
    for (int n = 0; n < 4; ++n) sa[n] = Z4;
#pragma unroll
    for (int n = 0; n < 4; ++n) {
      int krow = n * 16 + r16;
#pragma unroll
      for (int kc = 0; kc < 2; ++kc) {
        f16x8 kf = *(const f16x8*)(Kt + krow * 64 + (((kc * 4 + g4) ^ (krow & 7)) << 3));
        sa[n] = __builtin_amdgcn_mfma_f32_16x16x32_f16(qf[kc], kf, sa[n], 0, 0, 0);
      }
    }
#pragma unroll
    for (int r = 0; r < 4; ++r) {
      float mx = -1e30f;
#pragma unroll
      for (int n = 0; n < 4; ++n) {
        int key = kt + n * 16 + r16;
        float sv = (key < SEQ) ? sa[n][r] * SCALE_ : -1e30f;
        sa[n][r] = sv;
        mx = fmaxf(mx, sv);
      }
#pragma unroll
      for (int d = 1; d < 16; d <<= 1) mx = fmaxf(mx, __shfl_xor(mx, d));
      // defer-max (T13): only rescale when some row's max grew by > 8
      if (!__all(mx - m_run[r] <= 8.f)) {
        float mnew = fmaxf(m_run[r], mx);
        float alpha = __expf(m_run[r] - mnew);
        m_run[r] = mnew;
        l_run[r] *= alpha;
#pragma unroll
        for (int n = 0; n < 4; ++n) o_acc[n][r] *= alpha;
      }
      float ssum = 0.f;
#pragma unroll
      for (int n = 0; n < 4; ++n) {
        float p = __expf(sa[n][r] - m_run[r]);   // bounded by e^8
        ssum += p;
        Pw[wv][g4 * 4 + r][n * 16 + r16] = (f16)p;
      }
#pragma unroll
      for (int d = 1; d < 16; d <<= 1) ssum += __shfl_xor(ssum, d);
      l_run[r] += ssum;
    }
    f16x8 pf[2];
    pf[0] = *(const f16x8*)(&Pw[wv][r16][g4 * 8]);
    pf[1] = *(const f16x8*)(&Pw[wv][r16][32 + g4 * 8]);
#pragma unroll
    for (int n = 0; n < 4; ++n) {
      int erow = n * 16 + r16;
#pragma unroll
      for (int kc = 0; kc < 2; ++kc) {
        f16x8 vf = *(const f16x8*)(Vt + erow * 64 + (((kc * 4 + g4) ^ (erow & 7)) << 3));
        o_acc[n] = __builtin_amdgcn_mfma_f32_16x16x32_f16(pf[kc], vf, o_acc[n], 0, 0, 0);
      }
    }
    __syncthreads();
  }
  float inv[4];
#pragma unroll
  for (int r = 0; r < 4; ++r) inv[r] = 1.f / l_run[r];
#pragma unroll
  for (int n = 0; n < 4; ++n)
#pragma unroll
    for (int r = 0; r < 4; ++r) {
      int s = s0 + wv * 16 + g4 * 4 + r;
      if (s < SEQ)
        obuf[((size_t)(b * SEQ + s)) * 768 + hd * 64 + n * 16 + r16] =
            (f16)(o_acc[n][r] * inv[r]);
    }
}

// ---------------- weight converts (blockIdx.z = layer) ----------------
__global__ __launch_bounds__(256) void cvt_transpose(const float* __restrict__ in,
    f16* __restrict__ out, int K, int N, size_t ls_in, size_t ls_out)
{
  in  += (size_t)blockIdx.z * ls_in;
  out += (size_t)blockIdx.z * ls_out;
  __shared__ float t[32][33];
  int n0 = blockIdx.x << 5, k0 = blockIdx.y << 5;
  int tx = threadIdx.x & 31, ty = threadIdx.x >> 5;
#pragma unroll
  for (int i = 0; i < 4; ++i) t[ty + 8*i][tx] = in[(size_t)(k0 + ty + 8*i) * N + n0 + tx];
  __syncthreads();
#pragma unroll
  for (int i = 0; i < 4; ++i) out[(size_t)(n0 + ty + 8*i) * K + k0 + tx] = (f16)t[tx][ty + 8*i];
}

__global__ __launch_bounds__(256) void cvt_qkvw(const float* __restrict__ in,
    f16* __restrict__ out, size_t ls_in, size_t ls_out)
{
  in  += (size_t)blockIdx.z * ls_in;
  out += (size_t)blockIdx.z * ls_out;
  __shared__ float t[32][33];
  int n0 = blockIdx.x << 5, k0 = blockIdx.y << 5;
  int tx = threadIdx.x & 31, ty = threadIdx.x >> 5;
  int hq = n0 / 192, r0 = n0 - hq * 192;
#pragma unroll
  for (int i = 0; i < 4; ++i)
    t[ty + 8*i][tx] = in[(size_t)hq * 147456 + (size_t)(k0 + ty + 8*i) * 192 + r0 + tx];
  __syncthreads();
#pragma unroll
  for (int i = 0; i < 4; ++i) out[(size_t)(n0 + ty + 8*i) * 768 + k0 + tx] = (f16)t[tx][ty + 8*i];
}

__global__ __launch_bounds__(256) void cvt_plain(const float* __restrict__ in,
    f16* __restrict__ out, int n)
{
  int i = blockIdx.x * 1024 + threadIdx.x;
#pragma unroll
  for (int j = 0; j < 4; ++j) { int idx = i + j * 256; if (idx < n) out[idx] = (f16)in[idx]; }
}

__global__ __launch_bounds__(256) void zero_vpad(f16* __restrict__ vtb) {
  int bh = blockIdx.x;
  for (int idx = threadIdx.x; idx < 64 * (SPAD - SEQ); idx += 256) {
    int e = idx / (SPAD - SEQ), s = SEQ + idx - e * (SPAD - SEQ);
    vtb[((size_t)bh * 64 + e) * SPAD + s] = (f16)0.f;
  }
}

// ---------------- patchify (im2col) & cls ----------------
__global__ __launch_bounds__(256) void im2col_k(const float* __restrict__ x, f16* __restrict__ out) {
  int row = blockIdx.x;
  int b = row / 576, p = row - b * 576;
  int py = p / 24, px = p - py * 24;
  int tid = threadIdx.x;
#pragma unroll
  for (int j = 0; j < 3; ++j) {
    int k = tid + j * 256;
    int c = k >> 8, rem = k & 255;
    int iy = rem >> 4, ix = rem & 15;
    out[(size_t)row * 768 + k] =
        (f16)x[(((size_t)(b * 3 + c)) * 384 + py * 16 + iy) * 384 + px * 16 + ix];
  }
}

__global__ __launch_bounds__(256) void cls_k(const float* __restrict__ ct,
    const float* __restrict__ pos, float* __restrict__ X)
{
  int b = blockIdx.x, tid = threadIdx.x;
#pragma unroll
  for (int j = 0; j < 3; ++j) {
    int d0 = tid + j * 256;
    X[((size_t)b * SEQ) * 768 + d0] = ct[d0] + pos[d0];
  }
}

// ---------------- classifier head: logits (grid 32 x 4) + softmax (grid 32) ----------------
__global__ __launch_bounds__(256) void head_logits(const float* __restrict__ X,
    const float* __restrict__ g, const float* __restrict__ bb,
    const float* __restrict__ W, const float* __restrict__ bhd,
    float* __restrict__ lg)
{
  int b = blockIdx.x, tid = threadIdx.x;
  const float* x = X + (size_t)(b * SEQ) * 768;
  float v0 = x[tid], v1 = x[tid + 256], v2 = x[tid + 512];
  float s = v0 + v1 + v2, s2 = v0*v0 + v1*v1 + v2*v2;
  __shared__ float sm[8];
  block_red2(s, s2, sm, tid);
  float mu = s * (1.f/768.f), var = s2 * (1.f/768.f) - mu * mu;
  float rs = rsqrtf(var + 1e-5f);
  __shared__ float y[768];
  y[tid      ] = (v0 - mu) * rs * g[tid      ] + bb[tid      ];
  y[tid + 256] = (v1 - mu) * rs * g[tid + 256] + bb[tid + 256];
  y[tid + 512] = (v2 - mu) * rs * g[tid + 512] + bb[tid + 512];
  __syncthreads();
  int c = blockIdx.y * 250 + tid;
  if (tid < 250) {
    float a0 = 0.f, a1 = 0.f, a2 = 0.f, a3 = 0.f;
#pragma unroll 4
    for (int d = 0; d < 768; d += 4) {
      a0 = fmaf(y[d    ], W[(size_t)(d    ) * 1000 + c], a0);
      a1 = fmaf(y[d + 1], W[(size_t)(d + 1) * 1000 + c], a1);
      a2 = fmaf(y[d + 2], W[(size_t)(d + 2) * 1000 + c], a2);
      a3 = fmaf(y[d + 3], W[(size_t)(d + 3) * 1000 + c], a3);
    }
    lg[(size_t)b * 1000 + c] = (a0 + a1) + (a2 + a3) + bhd[c];
  }
}

__global__ __launch_bounds__(256) void head_soft(const float* __restrict__ lg,
    float* __restrict__ out)
{
  int b = blockIdx.x, tid = threadIdx.x;
  __shared__ float sm[8];
  float v[4], mx = -1e30f;
#pragma unroll
  for (int j = 0; j < 4; ++j) {
    int c = tid + j * 256;
    v[j] = (c < 1000) ? lg[(size_t)b * 1000 + c] : -1e30f;
    mx = fmaxf(mx, v[j]);
  }
#pragma unroll
  for (int d = 32; d; d >>= 1) mx = fmaxf(mx, __shfl_down(mx, d));
  if ((tid & 63) == 0) sm[tid >> 6] = mx;
  __syncthreads();
  mx = fmaxf(fmaxf(sm[0], sm[1]), fmaxf(sm[2], sm[3]));
  float se = 0.f, ex[4];
#pragma unroll
  for (int j = 0; j < 4; ++j) {
    int c = tid + j * 256;
    ex[j] = (c < 1000) ? __expf(v[j] - mx) : 0.f;
    se += ex[j];
  }
  __syncthreads();
#pragma unroll
  for (int d = 32; d; d >>= 1) se += __shfl_down(se, d);
  if ((tid & 63) == 0) sm[tid >> 6] = se;
  __syncthreads();
  se = sm[0] + sm[1] + sm[2] + sm[3];
  float inv = 1.f / se;
#pragma unroll
  for (int j = 0; j < 4; ++j) {
    int c = tid + j * 256;
    if (c < 1000) out[(size_t)b * 1000 + c] = ex[j] * inv;
  }
}

// ---------------- launcher ----------------
extern "C" void kernel_launch(void* const* d_in, const int* in_sizes, int n_in,
                              void* d_out, int out_size, void* d_ws, size_t ws_size,
                              hipStream_t stream)
{
  (void)in_sizes; (void)n_in; (void)out_size;
  const float* x      = (const float*)d_in[0];
  const float* conv_w = (const float*)d_in[1];
  const float* conv_b = (const float*)d_in[2];
  const float* cls_t  = (const float*)d_in[3];
  const float* pos    = (const float*)d_in[4];
  const float* ln1_g  = (const float*)d_in[5];
  const float* ln1_b  = (const float*)d_in[6];
  const float* wqkv   = (const float*)d_in[7];
  const float* bqkv   = (const float*)d_in[8];
  const float* wmsa   = (const float*)d_in[9];
  const float* bmsa   = (const float*)d_in[10];
  const float* ln2_g  = (const float*)d_in[11];
  const float* ln2_b  = (const float*)d_in[12];
  const float* lnm_g  = (const float*)d_in[13];
  const float* lnm_b  = (const float*)d_in[14];
  const float* w1     = (const float*)d_in[15];
  const float* b1     = (const float*)d_in[16];
  const float* w2     = (const float*)d_in[17];
  const float* b2     = (const float*)d_in[18];
  const float* lnf_g  = (const float*)d_in[19];
  const float* lnf_b  = (const float*)d_in[20];
  const float* whead  = (const float*)d_in[21];
  const float* bhead  = (const float*)d_in[22];
  float* out = (float*)d_out;

  const size_t szQ  = (size_t)2304 * 768;
  const size_t szM  = (size_t)768 * 768;
  const size_t szW1 = (size_t)3072 * 768;
  const size_t szW2 = (size_t)768 * 3072;
  const size_t fixed_bytes =
      (size_t)MPAD * 768 * 4 + (size_t)MPAD * 8 + 32 * 1000 * 4 +
      (size_t)MPAD * 768 * 2 +
      (size_t)MPAD * 3072 * 2 + 3 * ((size_t)NBATCH * NHEAD * SPAD * 64 * 2) +
      (size_t)768 * 768 * 2 /*WcT*/ + 16 * 256 /*align slack*/;
  const bool hoist =
      ws_size >= fixed_bytes + 12 * (szQ + szM + szW1 + szW2) * 2 + 8 * 256;
  const int LW = hoist ? 12 : 1;

  char* wsp = (char*)d_ws;
  size_t off = 0;
  auto alloc = [&](size_t bytes) {
    char* p = wsp + off; off += (bytes + 255) & ~(size_t)255; return p;
  };
  float* X    = (float*)alloc((size_t)MPAD * 768 * 4);
  float* stats= (float*)alloc((size_t)MPAD * 8);
  float* lgbuf= (float*)alloc((size_t)32 * 1000 * 4);
  f16*   hh   = (f16*)  alloc((size_t)MPAD * 768 * 2);
  f16*   abuf = (f16*)  alloc((size_t)MPAD * 3072 * 2);
  f16*   qb   = (f16*)  alloc((size_t)NBATCH * NHEAD * SPAD * 64 * 2);
  f16*   kb   = (f16*)  alloc((size_t)NBATCH * NHEAD * SPAD * 64 * 2);
  f16*   vtb  = (f16*)  alloc((size_t)NBATCH * NHEAD * SPAD * 64 * 2);
  f16*   WcT  = (f16*)  alloc((size_t)768 * 768 * 2);
  f16*   WqkvT= (f16*)  alloc(LW * szQ  * 2);
  f16*   WmsaT= (f16*)  alloc(LW * szM  * 2);
  f16*   W1T  = (f16*)  alloc(LW * szW1 * 2);
  f16*   W2T  = (f16*)  alloc(LW * szW2 * 2);
  f16*   obuf   = abuf;   // alias: attn out, consumed by MSA before FC1 writes abuf
  f16*   patchA = abuf;   // alias: im2col buffer, consumed by conv GEMM pre-loop
  f16*   h2h    = hh;     // alias: hh dead after QKV GEMM each layer
  if (ws_size < off) return;  // workspace too small: bail (bench will flag)

  zero_vpad<<<dim3(NBATCH * NHEAD), 256, 0, stream>>>(vtb);
  cvt_plain<<<dim3((768 * 768 + 1023) / 1024), 256, 0, stream>>>(conv_w, WcT, 768 * 768);
  if (hoist) {  // convert all 12 layers' weights up front
    cvt_qkvw<<<dim3(72, 24, 12), 256, 0, stream>>>(wqkv, WqkvT, (size_t)12*768*192, szQ);
    cvt_transpose<<<dim3(24, 24, 12), 256, 0, stream>>>(wmsa, WmsaT, 768, 768, szM, szM);
    cvt_transpose<<<dim3(96, 24, 12), 256, 0, stream>>>(w1, W1T, 768, 3072, szW1, szW1);
    cvt_transpose<<<dim3(24, 96, 12), 256, 0, stream>>>(w2, W2T, 3072, 768, szW2, szW2);
  }
  im2col_k<<<dim3(MCONV), 256, 0, stream>>>(x, patchA);
  gemm_k<768, 0><<<dim3(6, 144), 256, 0, stream>>>(
      patchA, WcT, conv_b, nullptr, X, nullptr, nullptr, nullptr, pos,
      nullptr, nullptr, nullptr, 768, MCONV);
  cls_k<<<dim3(NBATCH), 256, 0, stream>>>(cls_t, pos, X);

  for (int l = 0; l < 12; ++l) {
    f16* wq  = WqkvT + (hoist ? (size_t)l * szQ  : 0);
    f16* wms = WmsaT + (hoist ? (size_t)l * szM  : 0);
    f16* w1t = W1T   + (hoist ? (size_t)l * szW1 : 0);
    f16* w2t = W2T   + (hoist ? (size_t)l * szW2 : 0);
    if (!hoist) {
      cvt_qkvw<<<dim3(72, 24), 256, 0, stream>>>(
          wqkv + (size_t)l * 12 * 768 * 192, wq, 0, 0);
      cvt_transpose<<<dim3(24, 24), 256, 0, stream>>>(
          wmsa + (size_t)l * 768 * 768, wms, 768, 768, 0, 0);
      cvt_transpose<<<dim3(96, 24), 256, 0, stream>>>(
          w1 + (size_t)l * 768 * 3072, w1t, 768, 3072, 0, 0);
      cvt_transpose<<<dim3(24, 96), 256, 0, stream>>>(
          w2 + (size_t)l * 3072 * 768, w2t, 3072, 768, 0, 0);
    }

    ln_fwd<<<dim3(MREAL), 256, 0, stream>>>(X, ln1_g + l * 768, ln1_b + l * 768, stats, hh);
    gemm_k<768, 1><<<dim3(18, 145), 256, 0, stream>>>(
        hh, wq, bqkv + (size_t)l * 2304, nullptr, nullptr, qb, kb, vtb, nullptr,
        nullptr, nullptr, nullptr, 2304, MREAL);
    attn_k<<<dim3(10, NBATCH * NHEAD), 256, 0, stream>>>(qb, kb, vtb, obuf);
    gemm_k<768, 4><<<dim3(6, 145), 256, 0, stream>>>(
        obuf, wms, bmsa + l * 768, X, X, nullptr, nullptr, nullptr, nullptr,
        ln1_g + l * 768, ln1_b + l * 768, stats, 768, MREAL);
    ln2_fwd<<<dim3(MREAL), 256, 0, stream>>>(
        X, ln2_g + l * 768, ln2_b + l * 768, lnm_g + l * 768, lnm_b + l * 768, h2h);
    gemm_k<768, 3><<<dim3(24, 145), 256, 0, stream>>>(
        h2h, w1t, b1 + (size_t)l * 3072, nullptr, nullptr, abuf, nullptr, nullptr, nullptr,
        nullptr, nullptr, nullptr, 3072, MREAL);
    gemm_k<3072, 2><<<dim3(6, 145), 256, 0, stream>>>(
        abuf, w2t, b2 + l * 768, X, X, nullptr, nullptr, nullptr, nullptr,
        nullptr, nullptr, nullptr, 768, MREAL);
  }
  head_logits<<<dim3(NBATCH, 4), 256, 0, stream>>>(X, lnf_g, lnf_b, whead, bhead, lgbuf);
  head_soft<<<dim3(NBATCH), 256, 0, stream>>>(lgbuf, out);
}

// Round 9
// 7829.292 us; speedup vs baseline: 1.0809x; 1.0477x over previous
//
#include <hip/hip_runtime.h>

// ---------------- types ----------------
using f16   = _Float16;
using f16x8 = __attribute__((ext_vector_type(8))) _Float16;
using f32x4 = __attribute__((ext_vector_type(4))) float;

#define MPAD  18560          // 145*128, padded token rows
#define MREAL 18464          // 32*577
#define MCONV 18432          // 32*576
#define SEQ   577
#define SPAD  640
#define NHEAD 12
#define NBATCH 32
#define SC2   0.18033688f    // (1/sqrt(64)) * log2(e): exp2-domain scale
#define THR2  11.5416f       // defer-max threshold 8 * log2(e)

__device__ __forceinline__ void load_lds16(const void* g, void* l) {
  __builtin_amdgcn_global_load_lds(
      (const __attribute__((address_space(1))) void*)g,
      (__attribute__((address_space(3))) void*)l, 16, 0, 0);
}

// ---------------- GEMM: C[M,N] = A[M,K] * Bt[N,K]^T, fused epilogues ----------------
// BK=64 conflict-free LDS layout (128B rows = 32 banks; verified 0 conflicts)
// + m97-style single-buffer 2-barrier loop (round-8, best measured).
// Block ordering: bijective XCD chunking (m204) + M-major decode within
// 6-N-tile bands (B band L2-resident). Requires gridDim.x % 6 == 0.
// EPI 0: conv embed (scramble + conv_b + pos_emb -> o32=X)
// EPI 1: qkv scatter (bias; q->o16a [bh][s][e], k->o16b [bh][s][e], v->o16c [bh][e][s])
// EPI 2: bias + raw residual -> o32 (fp32)               (FC2: res = X)
// EPI 3: bias + exact gelu -> o16a (fp16)                (FC1)
// EPI 4: bias + LN1-recomputed residual -> o32 (fp32)    (MSA: h from X,stats)
template<int K, int EPI>
__global__ __launch_bounds__(256) void gemm_k(
    const f16* __restrict__ A, const f16* __restrict__ Bt,
    const float* __restrict__ bias, const float* __restrict__ res,
    float* __restrict__ o32, f16* __restrict__ o16a, f16* __restrict__ o16b,
    f16* __restrict__ o16c, const float* __restrict__ pos,
    const float* __restrict__ lng, const float* __restrict__ lnb,
    const float* __restrict__ stats, int N, int Mreal)
{
  static_assert(K % 64 == 0, "BK=64");
  __shared__ __align__(16) f16 As[128 * 64];
  __shared__ __align__(16) f16 Bs[128 * 64];
  const int tid = threadIdx.x;
  const int lane = tid & 63, wv = tid >> 6;

  // XCD chunking + band-supertile decode
  const int gx = gridDim.x, gy = gridDim.y;
  const int nwg = gx * gy;
  const int flat = blockIdx.y * gx + blockIdx.x;
  const int xcd = flat & 7;
  const int qq = nwg >> 3, rr = nwg & 7;
  const int p_ = ((xcd < rr) ? xcd * (qq + 1) : rr * (qq + 1) + (xcd - rr) * qq)
                 + (flat >> 3);
  const int bandsz = gy * 6;
  const int band = p_ / bandsz, within = p_ - band * bandsz;
  const int byi = within / 6;
  const int bxi = band * 6 + (within - byi * 6);
  const int bm = byi << 7, bn = bxi << 7;

  const int wm = (wv >> 1) << 6, wn = (wv & 1) << 6;
  const int r16 = lane & 15, g4 = lane >> 4;
  const f32x4 Z4 = {0.f, 0.f, 0.f, 0.f};

  f32x4 acc[4][4];
#pragma unroll
  for (int m = 0; m < 4; ++m)
#pragma unroll
    for (int n = 0; n < 4; ++n) acc[m][n] = Z4;

  // staging: each gload_lds = 64 lanes x 16B = 8 rows x 128B, wave-linear dest.
  const int srow = lane >> 3;          // 0..7
  const int sgc  = (lane & 7) ^ srow;  // pre-swizzled global chunk
  const f16* Agp = A  + (size_t)(bm + srow) * K + sgc * 8;
  const f16* Bgp = Bt + (size_t)(bn + srow) * K + sgc * 8;

  for (int k0 = 0; k0 < K; k0 += 64) {
#pragma unroll
    for (int j = 0; j < 4; ++j) {
      const size_t roff = (size_t)((wv * 4 + j) * 8) * K + k0;
      load_lds16(Agp + roff, As + (wv * 4 + j) * 512);
      load_lds16(Bgp + roff, Bs + (wv * 4 + j) * 512);
    }
    __syncthreads();
#pragma unroll
    for (int ks = 0; ks < 2; ++ks) {
      f16x8 af[4], bf[4];
#pragma unroll
      for (int m = 0; m < 4; ++m) {
        int row = wm + m * 16 + r16;
        af[m] = *(const f16x8*)(As + row * 64 + ((((ks << 2) | g4) ^ (row & 7)) << 3));
      }
#pragma unroll
      for (int n = 0; n < 4; ++n) {
        int row = wn + n * 16 + r16;
        bf[n] = *(const f16x8*)(Bs + row * 64 + ((((ks << 2) | g4) ^ (row & 7)) << 3));
      }
#pragma unroll
      for (int m = 0; m < 4; ++m)
#pragma unroll
        for (int n = 0; n < 4; ++n)
          acc[m][n] = __builtin_amdgcn_mfma_f32_16x16x32_f16(af[m], bf[n], acc[m][n], 0, 0, 0);
    }
    __syncthreads();
  }

#pragma unroll
  for (int m = 0; m < 4; ++m) {
#pragma unroll
    for (int n = 0; n < 4; ++n) {
#pragma unroll
      for (int r = 0; r < 4; ++r) {
        int grow = bm + wm + m * 16 + g4 * 4 + r;
        int gcol = bn + wn + n * 16 + r16;
        float v = acc[m][n][r];
        if constexpr (EPI == 0) {
          if (grow < Mreal) {
            int b = grow / 576, p = grow - b * 576;
            int i = gcol * 576 + p;               // channel-major flat index
            int sp = i / 768, dd = i - sp * 768;  // faithful .view(b,-1,D) scramble
            o32[((size_t)(b * SEQ + sp + 1)) * 768 + dd] =
                v + bias[gcol] + pos[(size_t)(sp + 1) * 768 + dd];
          }
        } else if constexpr (EPI == 1) {
          if (grow < Mreal) {
            int b = grow / SEQ, s = grow - b * SEQ;
            int hq = gcol / 192, rem = gcol - hq * 192;
            int sel = rem >> 6, e = rem & 63;
            float val = v + bias[gcol];
            int bh = b * NHEAD + hq;
            if (sel == 0)      o16a[((size_t)bh * SPAD + s) * 64 + e] = (f16)val;
            else if (sel == 1) o16b[((size_t)bh * SPAD + s) * 64 + e] = (f16)val;
            else               o16c[((size_t)bh * 64 + e) * SPAD + s] = (f16)val;  // V transposed
          }
        } else if constexpr (EPI == 2) {
          size_t idx = (size_t)grow * N + gcol;
          o32[idx] = v + bias[gcol] + res[idx];
        } else if constexpr (EPI == 4) {
          if (grow < Mreal) {
            size_t idx = (size_t)grow * N + gcol;
            float mu = stats[2 * grow], rs = stats[2 * grow + 1];
            float h = (res[idx] - mu) * rs * lng[gcol] + lnb[gcol];
            o32[idx] = v + bias[gcol] + h;
          }
        } else {
          float val = v + bias[gcol];
          float gl = 0.5f * val * (1.0f + erff(val * 0.70710678f));
          o16a[(size_t)grow * N + gcol] = (f16)gl;
        }
      }
    }
  }
}

// ---------------- block reduce helper ----------------
__device__ __forceinline__ void block_red2(float& a, float& b, float* sm, int tid) {
  __syncthreads();
#pragma unroll
  for (int d = 32; d; d >>= 1) { a += __shfl_down(a, d); b += __shfl_down(b, d); }
  if ((tid & 63) == 0) { int w = tid >> 6; sm[w] = a; sm[w + 4] = b; }
  __syncthreads();
  a = sm[0] + sm[1] + sm[2] + sm[3];
  b = sm[4] + sm[5] + sm[6] + sm[7];
}

// ---------------- LayerNorm (fp32 in -> fp16 out + per-row stats) ----------------
__global__ __launch_bounds__(256) void ln_fwd(const float* __restrict__ X,
    const float* __restrict__ g, const float* __restrict__ bb,
    float* __restrict__ stats, f16* __restrict__ hh)
{
  int row = blockIdx.x, tid = threadIdx.x;
  const float* x = X + (size_t)row * 768;
  float v0 = x[tid], v1 = x[tid + 256], v2 = x[tid + 512];
  float s = v0 + v1 + v2, s2 = v0*v0 + v1*v1 + v2*v2;
  __shared__ float sm[8];
  block_red2(s, s2, sm, tid);
  float mu = s * (1.f/768.f);
  float var = s2 * (1.f/768.f) - mu * mu;
  float rs = rsqrtf(var + 1e-5f);
  if (tid == 0) { stats[2 * row] = mu; stats[2 * row + 1] = rs; }
  size_t base = (size_t)row * 768;
  hh[base + tid      ] = (f16)((v0 - mu) * rs * g[tid      ] + bb[tid      ]);
  hh[base + tid + 256] = (f16)((v1 - mu) * rs * g[tid + 256] + bb[tid + 256]);
  hh[base + tid + 512] = (f16)((v2 - mu) * rs * g[tid + 512] + bb[tid + 512]);
}

// ---------------- Double LayerNorm (LN(LN(x))) -> fp16 ----------------
__global__ __launch_bounds__(256) void ln2_fwd(const float* __restrict__ X,
    const float* __restrict__ g2, const float* __restrict__ bb2,
    const float* __restrict__ gm, const float* __restrict__ bbm,
    f16* __restrict__ hh)
{
  int row = blockIdx.x, tid = threadIdx.x;
  const float* x = X + (size_t)row * 768;
  float v0 = x[tid], v1 = x[tid + 256], v2 = x[tid + 512];
  float s = v0 + v1 + v2, s2 = v0*v0 + v1*v1 + v2*v2;
  __shared__ float sm[8];
  block_red2(s, s2, sm, tid);
  float mu = s * (1.f/768.f), var = s2 * (1.f/768.f) - mu * mu;
  float rs = rsqrtf(var + 1e-5f);
  float y0 = (v0 - mu) * rs * g2[tid      ] + bb2[tid      ];
  float y1 = (v1 - mu) * rs * g2[tid + 256] + bb2[tid + 256];
  float y2 = (v2 - mu) * rs * g2[tid + 512] + bb2[tid + 512];
  s = y0 + y1 + y2; s2 = y0*y0 + y1*y1 + y2*y2;
  block_red2(s, s2, sm, tid);
  mu = s * (1.f/768.f); var = s2 * (1.f/768.f) - mu * mu;
  rs = rsqrtf(var + 1e-5f);
  size_t base = (size_t)row * 768;
  hh[base + tid      ] = (f16)((y0 - mu) * rs * gm[tid      ] + bbm[tid      ]);
  hh[base + tid + 256] = (f16)((y1 - mu) * rs * gm[tid + 256] + bbm[tid + 256]);
  hh[base + tid + 512] = (f16)((y2 - mu) * rs * gm[tid + 512] + bbm[tid + 512]);
}

// ---------------- flash attention (64 q-rows / block; exp2 softmax, deferred
// l-reduce, defer-max, masked-tail split, XCD bh-grouping) ----------------
__global__ __launch_bounds__(256) void attn_k(const f16* __restrict__ qbuf,
    const f16* __restrict__ kbuf, const f16* __restrict__ vtbuf,
    f16* __restrict__ obuf)
{
  // bijective XCD remap: all 10 s0-blocks of one head land on one XCD
  // (K/V stays L2-resident). nwg = 3840, divisible by 8.
  const int gx = gridDim.x;                       // 10
  const int nwg = gx * gridDim.y;
  const int flat = blockIdx.y * gx + blockIdx.x;
  const int xcd = flat & 7;
  const int qq = nwg >> 3, rr = nwg & 7;
  const int pos_ = ((xcd < rr) ? xcd * (qq + 1) : rr * (qq + 1) + (xcd - rr) * qq)
                   + (flat >> 3);
  const int bh = pos_ / gx;
  const int s0 = (pos_ - bh * gx) << 6;

  const int b = bh / NHEAD, hd = bh - b * NHEAD;
  const int tid = threadIdx.x, lane = tid & 63, wv = tid >> 6;
  const int r16 = lane & 15, g4 = lane >> 4;
  const f16* Q  = qbuf  + (size_t)bh * SPAD * 64;
  const f16* Kg = kbuf  + (size_t)bh * SPAD * 64;
  const f16* Vg = vtbuf + (size_t)bh * 64 * SPAD;
  __shared__ __align__(16) f16 Kt[64 * 64];
  __shared__ __align__(16) f16 Vt[64 * 64];
  __shared__ __align__(16) f16 Pw[4][16][72];
  const f32x4 Z4 = {0.f, 0.f, 0.f, 0.f};

  f16x8 qf[2];
  {
    const f16* qr = Q + (size_t)(s0 + wv * 16 + r16) * 64;
    qf[0] = *(const f16x8*)(qr + g4 * 8);
    qf[1] = *(const f16x8*)(qr + 32 + g4 * 8);
  }
  float m_run[4] = {-1e30f, -1e30f, -1e30f, -1e30f};
  float l_part[4] = {0.f, 0.f, 0.f, 0.f};   // per-lane partial; reduced once at end
  f32x4 o_acc[4];
#pragma unroll
  for (int n = 0; n < 4; ++n) o_acc[n] = Z4;

  auto tile = [&](int kt, bool mask) {
#pragma unroll
    for (int j = 0; j < 2; ++j) {
      int off = (wv * 2 + j) * 1024 + lane * 16;  // bytes
      int row = off >> 7;
      int cs  = (off >> 4) & 7;
      int gc  = cs ^ (row & 7);                   // 8-chunk XOR swizzle
      load_lds16(Kg + (size_t)(kt + row) * 64 + gc * 8, (void*)((char*)Kt + (wv*2 + j) * 1024));
      load_lds16(Vg + (size_t)row * SPAD + kt + gc * 8, (void*)((char*)Vt + (wv*2 + j) * 1024));
    }
    __syncthreads();

    f32x4 sa[4];
#pragma unroll
    for (int n = 0; n < 4; ++n) sa[n] = Z4;
#pragma unroll
    for (int n = 0; n < 4; ++n) {
      int krow = n * 16 + r16;
#pragma unroll
      for (int kc = 0; kc < 2; ++kc) {
        f16x8 kf = *(const f16x8*)(Kt + krow * 64 + (((kc * 4 + g4) ^ (krow & 7)) << 3));
        sa[n] = __builtin_amdgcn_mfma_f32_16x16x32_f16(qf[kc], kf, sa[n], 0, 0, 0);
      }
    }
#pragma unroll
    for (int r = 0; r < 4; ++r) {
      float mx = -1e30f;
#pragma unroll
      for (int n = 0; n < 4; ++n) {
        float sv = sa[n][r] * SC2;                 // exp2 domain
        if (mask && (kt + n * 16 + r16 >= SEQ)) sv = -1e30f;
        sa[n][r] = sv;
        mx = fmaxf(mx, sv);
      }
#pragma unroll
      for (int d = 1; d < 16; d <<= 1) mx = fmaxf(mx, __shfl_xor(mx, d));
      if (!__all(mx - m_run[r] <= THR2)) {         // defer-max (T13)
        float mnew = fmaxf(m_run[r], mx);
        float alpha = exp2f(m_run[r] - mnew);
        m_run[r] = mnew;
        l_part[r] *= alpha;
#pragma unroll
        for (int n = 0; n < 4; ++n) o_acc[n][r] *= alpha;
      }
#pragma unroll
      for (int n = 0; n < 4; ++n) {
        float p = exp2f(sa[n][r] - m_run[r]);      // bounded by 2^11.54
        l_part[r] += p;
        Pw[wv][g4 * 4 + r][n * 16 + r16] = (f16)p;
      }
    }
    f16x8 pf[2];
    pf[0] = *(const f16x8*)(&Pw[wv][r16][g4 * 8]);
    pf[1] = *(const f16x8*)(&Pw[wv][r16][32 + g4 * 8]);
#pragma unroll
    for (int n = 0; n < 4; ++n) {
      int erow = n * 16 + r16;
#pragma unroll
      for (int kc = 0; kc < 2; ++kc) {
        f16x8 vf = *(const f16x8*)(Vt + erow * 64 + (((kc * 4 + g4) ^ (erow & 7)) << 3));
        o_acc[n] = __builtin_amdgcn_mfma_f32_16x16x32_f16(pf[kc], vf, o_acc[n], 0, 0, 0);
      }
    }
    __syncthreads();
  };

#pragma unroll 1
  for (int kt = 0; kt < 576; kt += 64) tile(kt, false);  // tiles 0..8: no mask
  tile(576, true);                                        // tile 9: masked tail

  float inv[4];
#pragma unroll
  for (int r = 0; r < 4; ++r) {
    float l = l_part[r];
#pragma unroll
    for (int d = 1; d < 16; d <<= 1) l += __shfl_xor(l, d);
    inv[r] = 1.f / l;
  }
#pragma unroll
  for (int n = 0; n < 4; ++n)
#pragma unroll
    for (int r = 0; r < 4; ++r) {
      int s = s0 + wv * 16 + g4 * 4 + r;
      if (s < SEQ)
        obuf[((size_t)(b * SEQ + s)) * 768 + hd * 64 + n * 16 + r16] =
            (f16)(o_acc[n][r] * inv[r]);
    }
}

// ---------------- weight converts (blockIdx.z = layer) ----------------
__global__ __launch_bounds__(256) void cvt_transpose(const float* __restrict__ in,
    f16* __restrict__ out, int K, int N, size_t ls_in, size_t ls_out)
{
  in  += (size_t)blockIdx.z * ls_in;
  out += (size_t)blockIdx.z * ls_out;
  __shared__ float t[32][33];
  int n0 = blockIdx.x << 5, k0 = blockIdx.y << 5;
  int tx = threadIdx.x & 31, ty = threadIdx.x >> 5;
#pragma unroll
  for (int i = 0; i < 4; ++i) t[ty + 8*i][tx] = in[(size_t)(k0 + ty + 8*i) * N + n0 + tx];
  __syncthreads();
#pragma unroll
  for (int i = 0; i < 4; ++i) out[(size_t)(n0 + ty + 8*i) * K + k0 + tx] = (f16)t[tx][ty + 8*i];
}

__global__ __launch_bounds__(256) void cvt_qkvw(const float* __restrict__ in,
    f16* __restrict__ out, size_t ls_in, size_t ls_out)
{
  in  += (size_t)blockIdx.z * ls_in;
  out += (size_t)blockIdx.z * ls_out;
  __shared__ float t[32][33];
  int n0 = blockIdx.x << 5, k0 = blockIdx.y << 5;
  int tx = threadIdx.x & 31, ty = threadIdx.x >> 5;
  int hq = n0 / 192, r0 = n0 - hq * 192;
#pragma unroll
  for (int i = 0; i < 4; ++i)
    t[ty + 8*i][tx] = in[(size_t)hq * 147456 + (size_t)(k0 + ty + 8*i) * 192 + r0 + tx];
  __syncthreads();
#pragma unroll
  for (int i = 0; i < 4; ++i) out[(size_t)(n0 + ty + 8*i) * 768 + k0 + tx] = (f16)t[tx][ty + 8*i];
}

__global__ __launch_bounds__(256) void cvt_plain(const float* __restrict__ in,
    f16* __restrict__ out, int n)
{
  int i = blockIdx.x * 1024 + threadIdx.x;
#pragma unroll
  for (int j = 0; j < 4; ++j) { int idx = i + j * 256; if (idx < n) out[idx] = (f16)in[idx]; }
}

__global__ __launch_bounds__(256) void zero_vpad(f16* __restrict__ vtb) {
  int bh = blockIdx.x;
  for (int idx = threadIdx.x; idx < 64 * (SPAD - SEQ); idx += 256) {
    int e = idx / (SPAD - SEQ), s = SEQ + idx - e * (SPAD - SEQ);
    vtb[((size_t)bh * 64 + e) * SPAD + s] = (f16)0.f;
  }
}

// ---------------- patchify (im2col) & cls ----------------
__global__ __launch_bounds__(256) void im2col_k(const float* __restrict__ x, f16* __restrict__ out) {
  int row = blockIdx.x;
  int b = row / 576, p = row - b * 576;
  int py = p / 24, px = p - py * 24;
  int tid = threadIdx.x;
#pragma unroll
  for (int j = 0; j < 3; ++j) {
    int k = tid + j * 256;
    int c = k >> 8, rem = k & 255;
    int iy = rem >> 4, ix = rem & 15;
    out[(size_t)row * 768 + k] =
        (f16)x[(((size_t)(b * 3 + c)) * 384 + py * 16 + iy) * 384 + px * 16 + ix];
  }
}

__global__ __launch_bounds__(256) void cls_k(const float* __restrict__ ct,
    const float* __restrict__ pos, float* __restrict__ X)
{
  int b = blockIdx.x, tid = threadIdx.x;
#pragma unroll
  for (int j = 0; j < 3; ++j) {
    int d0 = tid + j * 256;
    X[((size_t)b * SEQ) * 768 + d0] = ct[d0] + pos[d0];
  }
}

// ---------------- classifier head: logits (grid 32 x 4) + softmax (grid 32) ----------------
__global__ __launch_bounds__(256) void head_logits(const float* __restrict__ X,
    const float* __restrict__ g, const float* __restrict__ bb,
    const float* __restrict__ W, const float* __restrict__ bhd,
    float* __restrict__ lg)
{
  int b = blockIdx.x, tid = threadIdx.x;
  const float* x = X + (size_t)(b * SEQ) * 768;
  float v0 = x[tid], v1 = x[tid + 256], v2 = x[tid + 512];
  float s = v0 + v1 + v2, s2 = v0*v0 + v1*v1 + v2*v2;
  __shared__ float sm[8];
  block_red2(s, s2, sm, tid);
  float mu = s * (1.f/768.f), var = s2 * (1.f/768.f) - mu * mu;
  float rs = rsqrtf(var + 1e-5f);
  __shared__ float y[768];
  y[tid      ] = (v0 - mu) * rs * g[tid      ] + bb[tid      ];
  y[tid + 256] = (v1 - mu) * rs * g[tid + 256] + bb[tid + 256];
  y[tid + 512] = (v2 - mu) * rs * g[tid + 512] + bb[tid + 512];
  __syncthreads();
  int c = blockIdx.y * 250 + tid;
  if (tid < 250) {
    float a0 = 0.f, a1 = 0.f, a2 = 0.f, a3 = 0.f;
#pragma unroll 4
    for (int d = 0; d < 768; d += 4) {
      a0 = fmaf(y[d    ], W[(size_t)(d    ) * 1000 + c], a0);
      a1 = fmaf(y[d + 1], W[(size_t)(d + 1) * 1000 + c], a1);
      a2 = fmaf(y[d + 2], W[(size_t)(d + 2) * 1000 + c], a2);
      a3 = fmaf(y[d + 3], W[(size_t)(d + 3) * 1000 + c], a3);
    }
    lg[(size_t)b * 1000 + c] = (a0 + a1) + (a2 + a3) + bhd[c];
  }
}

__global__ __launch_bounds__(256) void head_soft(const float* __restrict__ lg,
    float* __restrict__ out)
{
  int b = blockIdx.x, tid = threadIdx.x;
  __shared__ float sm[8];
  float v[4], mx = -1e30f;
#pragma unroll
  for (int j = 0; j < 4; ++j) {
    int c = tid + j * 256;
    v[j] = (c < 1000) ? lg[(size_t)b * 1000 + c] : -1e30f;
    mx = fmaxf(mx, v[j]);
  }
#pragma unroll
  for (int d = 32; d; d >>= 1) mx = fmaxf(mx, __shfl_down(mx, d));
  if ((tid & 63) == 0) sm[tid >> 6] = mx;
  __syncthreads();
  mx = fmaxf(fmaxf(sm[0], sm[1]), fmaxf(sm[2], sm[3]));
  float se = 0.f, ex[4];
#pragma unroll
  for (int j = 0; j < 4; ++j) {
    int c = tid + j * 256;
    ex[j] = (c < 1000) ? __expf(v[j] - mx) : 0.f;
    se += ex[j];
  }
  __syncthreads();
#pragma unroll
  for (int d = 32; d; d >>= 1) se += __shfl_down(se, d);
  if ((tid & 63) == 0) sm[tid >> 6] = se;
  __syncthreads();
  se = sm[0] + sm[1] + sm[2] + sm[3];
  float inv = 1.f / se;
#pragma unroll
  for (int j = 0; j < 4; ++j) {
    int c = tid + j * 256;
    if (c < 1000) out[(size_t)b * 1000 + c] = ex[j] * inv;
  }
}

// ---------------- launcher ----------------
extern "C" void kernel_launch(void* const* d_in, const int* in_sizes, int n_in,
                              void* d_out, int out_size, void* d_ws, size_t ws_size,
                              hipStream_t stream)
{
  (void)in_sizes; (void)n_in; (void)out_size;
  const float* x      = (const float*)d_in[0];
  const float* conv_w = (const float*)d_in[1];
  const float* conv_b = (const float*)d_in[2];
  const float* cls_t  = (const float*)d_in[3];
  const float* pos    = (const float*)d_in[4];
  const float* ln1_g  = (const float*)d_in[5];
  const float* ln1_b  = (const float*)d_in[6];
  const float* wqkv   = (const float*)d_in[7];
  const float* bqkv   = (const float*)d_in[8];
  const float* wmsa   = (const float*)d_in[9];
  const float* bmsa   = (const float*)d_in[10];
  const float* ln2_g  = (const float*)d_in[11];
  const float* ln2_b  = (const float*)d_in[12];
  const float* lnm_g  = (const float*)d_in[13];
  const float* lnm_b  = (const float*)d_in[14];
  const float* w1     = (const float*)d_in[15];
  const float* b1     = (const float*)d_in[16];
  const float* w2     = (const float*)d_in[17];
  const float* b2     = (const float*)d_in[18];
  const float* lnf_g  = (const float*)d_in[19];
  const float* lnf_b  = (const float*)d_in[20];
  const float* whead  = (const float*)d_in[21];
  const float* bhead  = (const float*)d_in[22];
  float* out = (float*)d_out;

  const size_t szQ  = (size_t)2304 * 768;
  const size_t szM  = (size_t)768 * 768;
  const size_t szW1 = (size_t)3072 * 768;
  const size_t szW2 = (size_t)768 * 3072;
  const size_t fixed_bytes =
      (size_t)MPAD * 768 * 4 + (size_t)MPAD * 8 + 32 * 1000 * 4 +
      (size_t)MPAD * 768 * 2 +
      (size_t)MPAD * 3072 * 2 + 3 * ((size_t)NBATCH * NHEAD * SPAD * 64 * 2) +
      (size_t)768 * 768 * 2 /*WcT*/ + 16 * 256 /*align slack*/;
  const bool hoist =
      ws_size >= fixed_bytes + 12 * (szQ + szM + szW1 + szW2) * 2 + 8 * 256;
  const int LW = hoist ? 12 : 1;

  char* wsp = (char*)d_ws;
  size_t off = 0;
  auto alloc = [&](size_t bytes) {
    char* p = wsp + off; off += (bytes + 255) & ~(size_t)255; return p;
  };
  float* X    = (float*)alloc((size_t)MPAD * 768 * 4);
  float* stats= (float*)alloc((size_t)MPAD * 8);
  float* lgbuf= (float*)alloc((size_t)32 * 1000 * 4);
  f16*   hh   = (f16*)  alloc((size_t)MPAD * 768 * 2);
  f16*   abuf = (f16*)  alloc((size_t)MPAD * 3072 * 2);
  f16*   qb   = (f16*)  alloc((size_t)NBATCH * NHEAD * SPAD * 64 * 2);
  f16*   kb   = (f16*)  alloc((size_t)NBATCH * NHEAD * SPAD * 64 * 2);
  f16*   vtb  = (f16*)  alloc((size_t)NBATCH * NHEAD * SPAD * 64 * 2);
  f16*   WcT  = (f16*)  alloc((size_t)768 * 768 * 2);
  f16*   WqkvT= (f16*)  alloc(LW * szQ  * 2);
  f16*   WmsaT= (f16*)  alloc(LW * szM  * 2);
  f16*   W1T  = (f16*)  alloc(LW * szW1 * 2);
  f16*   W2T  = (f16*)  alloc(LW * szW2 * 2);
  f16*   obuf   = abuf;   // alias: attn out, consumed by MSA before FC1 writes abuf
  f16*   patchA = abuf;   // alias: im2col buffer, consumed by conv GEMM pre-loop
  f16*   h2h    = hh;     // alias: hh dead after QKV GEMM each layer
  if (ws_size < off) return;  // workspace too small: bail (bench will flag)

  zero_vpad<<<dim3(NBATCH * NHEAD), 256, 0, stream>>>(vtb);
  cvt_plain<<<dim3((768 * 768 + 1023) / 1024), 256, 0, stream>>>(conv_w, WcT, 768 * 768);
  if (hoist) {  // convert all 12 layers' weights up front
    cvt_qkvw<<<dim3(72, 24, 12), 256, 0, stream>>>(wqkv, WqkvT, (size_t)12*768*192, szQ);
    cvt_transpose<<<dim3(24, 24, 12), 256, 0, stream>>>(wmsa, WmsaT, 768, 768, szM, szM);
    cvt_transpose<<<dim3(96, 24, 12), 256, 0, stream>>>(w1, W1T, 768, 3072, szW1, szW1);
    cvt_transpose<<<dim3(24, 96, 12), 256, 0, stream>>>(w2, W2T, 3072, 768, szW2, szW2);
  }
  im2col_k<<<dim3(MCONV), 256, 0, stream>>>(x, patchA);
  gemm_k<768, 0><<<dim3(6, 144), 256, 0, stream>>>(
      patchA, WcT, conv_b, nullptr, X, nullptr, nullptr, nullptr, pos,
      nullptr, nullptr, nullptr, 768, MCONV);
  cls_k<<<dim3(NBATCH), 256, 0, stream>>>(cls_t, pos, X);

  for (int l = 0; l < 12; ++l) {
    f16* wq  = WqkvT + (hoist ? (size_t)l * szQ  : 0);
    f16* wms = WmsaT + (hoist ? (size_t)l * szM  : 0);
    f16* w1t = W1T   + (hoist ? (size_t)l * szW1 : 0);
    f16* w2t = W2T   + (hoist ? (size_t)l * szW2 : 0);
    if (!hoist) {
      cvt_qkvw<<<dim3(72, 24), 256, 0, stream>>>(
          wqkv + (size_t)l * 12 * 768 * 192, wq, 0, 0);
      cvt_transpose<<<dim3(24, 24), 256, 0, stream>>>(
          wmsa + (size_t)l * 768 * 768, wms, 768, 768, 0, 0);
      cvt_transpose<<<dim3(96, 24), 256, 0, stream>>>(
          w1 + (size_t)l * 768 * 3072, w1t, 768, 3072, 0, 0);
      cvt_transpose<<<dim3(24, 96), 256, 0, stream>>>(
          w2 + (size_t)l * 3072 * 768, w2t, 3072, 768, 0, 0);
    }

    ln_fwd<<<dim3(MREAL), 256, 0, stream>>>(X, ln1_g + l * 768, ln1_b + l * 768, stats, hh);
    gemm_k<768, 1><<<dim3(18, 145), 256, 0, stream>>>(
        hh, wq, bqkv + (size_t)l * 2304, nullptr, nullptr, qb, kb, vtb, nullptr,
        nullptr, nullptr, nullptr, 2304, MREAL);
    attn_k<<<dim3(10, NBATCH * NHEAD), 256, 0, stream>>>(qb, kb, vtb, obuf);
    gemm_k<768, 4><<<dim3(6, 145), 256, 0, stream>>>(
        obuf, wms, bmsa + l * 768, X, X, nullptr, nullptr, nullptr, nullptr,
        ln1_g + l * 768, ln1_b + l * 768, stats, 768, MREAL);
    ln2_fwd<<<dim3(MREAL), 256, 0, stream>>>(
        X, ln2_g + l * 768, ln2_b + l * 768, lnm_g + l * 768, lnm_b + l * 768, h2h);
    gemm_k<768, 3><<<dim3(24, 145), 256, 0, stream>>>(
        h2h, w1t, b1 + (size_t)l * 3072, nullptr, nullptr, abuf, nullptr, nullptr, nullptr,
        nullptr, nullptr, nullptr, 3072, MREAL);
    gemm_k<3072, 2><<<dim3(6, 145), 256, 0, stream>>>(
        abuf, w2t, b2 + l * 768, X, X, nullptr, nullptr, nullptr, nullptr,
        nullptr, nullptr, nullptr, 768, MREAL);
  }
  head_logits<<<dim3(NBATCH, 4), 256, 0, stream>>>(X, lnf_g, lnf_b, whead, bhead, lgbuf);
  head_soft<<<dim3(NBATCH), 256, 0, stream>>>(lgbuf, out);
}